// Round 3
// baseline (580.864 us; speedup 1.0000x reference)
//
#include <hip/hip_runtime.h>

// (B, N, D, H) = (8, 4096, 256, 8), PS=8 -> image 64x64; blocked m=fine pos, n=tile idx.
// SPEC FACT 1: no softmax temperature; logit sigma ~16. f16 inputs + fp32 MFMA acc -> logit err ~0.01 (safe).
// SPEC FACT 2: Z = einsum('bhmnd,hdv->bmnd', O, o) is DIAGONAL in d, SUMS v:
//   Z[...,d] = sum_h O_h[...,d] * os[h][d], os[h][d] = sum_v o[h,d,v].
// SPEC FACT 3: S = (A M_h) A_g^T with M_h = q_h k^T. W = A·M_h computed IN-BLOCK in e-QUARTERS
//   (64x64 W sub-tile in a union W/P buffer) -> LDS 78 KB -> 2 blocks/CU (the round-2 kernel was
//   111 KB -> 1 block/CU -> 21% occupancy, barrier-latency-bound at MfmaUtil 16%).
// MFMA conventions (verified r6/r7, absmax 0.125): mfma_f32_16x16x32_f16 computes C = A @ B^T:
//   A-frag: A[m = l16][k = quad*8 + j]; B-frag same over n-rows; C/D: col = l16, row = quad*4 + reg.
// Z kept in BLOCKED layout, TWO buffers (mode0 heads 0-3, mode1 heads 4-7); ln2 sums them in fp32.
#define Bc   8
#define Tc   4096
#define Dc   256
#define EPSc 1e-5f

typedef _Float16 half_t;
typedef __attribute__((ext_vector_type(4))) _Float16 half4_t;
typedef __attribute__((ext_vector_type(8))) _Float16 frag8;
typedef __attribute__((ext_vector_type(4))) float f32x4;

#define MFMA_F16(a, b, c) __builtin_amdgcn_mfma_f32_16x16x32_f16((a), (b), (c), 0, 0, 0)

// ---------------- os[h][d] = sum_v o[h,d,v] ----------------
__global__ __launch_bounds__(256) void osum_kernel(const float* __restrict__ o, float* __restrict__ os) {
  int h = blockIdx.x, d = threadIdx.x;
  const float* row = o + ((size_t)h * 256 + d) * 256;
  float s = 0.f;
  #pragma unroll 8
  for (int v = 0; v < 256; v += 4) {
    float4 r4 = *(const float4*)&row[v];
    s += r4.x + r4.y + r4.z + r4.w;
  }
  os[h * 256 + d] = s;
}

// ---------------- Mt[h][e][d] = M_h[d][e] = sum_i q[h][d][i]*k[e][i]  (f16) ----------------
// Tiled fp32 GEMM: 512 blocks = h(8) x etile(8) x dtile(8); 32x32 output tile per block.
__global__ __launch_bounds__(256) void prepM_kernel(const float* __restrict__ q,
                                                    const float* __restrict__ k,
                                                    half_t* __restrict__ Mt) {
  __shared__ float shK[32 * 260];   // 32.5 KB
  __shared__ float shQ[32 * 260];   // 32.5 KB  (65 KB total -> 2 blocks/CU)
  int tid = threadIdx.x;
  int h = blockIdx.x >> 6, et = (blockIdx.x >> 3) & 7, dt = blockIdx.x & 7;
  const float* kbase = k + (size_t)(et * 32) * 256;
  const float* qbase = q + ((size_t)h * 256 + dt * 32) * 256;
  #pragma unroll
  for (int r = 0; r < 8; r++) {
    int f = r * 256 + tid;                  // float4 slot 0..2047; one row per wave
    int row = f >> 6, c4 = (f & 63) * 4;
    *(float4*)&shK[row * 260 + c4] = *(const float4*)&kbase[(size_t)row * 256 + c4];
    *(float4*)&shQ[row * 260 + c4] = *(const float4*)&qbase[(size_t)row * 256 + c4];
  }
  __syncthreads();
  int e = tid & 31, dg = tid >> 5;          // thread -> (e, 4 consecutive d)
  const float* kr = &shK[e * 260];
  const float* q0 = &shQ[(dg * 4 + 0) * 260];
  const float* q1 = &shQ[(dg * 4 + 1) * 260];
  const float* q2 = &shQ[(dg * 4 + 2) * 260];
  const float* q3 = &shQ[(dg * 4 + 3) * 260];
  float a0 = 0.f, a1 = 0.f, a2 = 0.f, a3 = 0.f;
  #pragma unroll 4
  for (int kk = 0; kk < 256; kk += 4) {
    float4 kv = *(const float4*)&kr[kk];
    float4 v0 = *(const float4*)&q0[kk];
    float4 v1 = *(const float4*)&q1[kk];
    float4 v2 = *(const float4*)&q2[kk];
    float4 v3 = *(const float4*)&q3[kk];
    a0 += v0.x * kv.x + v0.y * kv.y + v0.z * kv.z + v0.w * kv.w;
    a1 += v1.x * kv.x + v1.y * kv.y + v1.z * kv.z + v1.w * kv.w;
    a2 += v2.x * kv.x + v2.y * kv.y + v2.z * kv.z + v2.w * kv.w;
    a3 += v3.x * kv.x + v3.y * kv.y + v3.z * kv.z + v3.w * kv.w;
  }
  half4_t outv;
  outv[0] = (half_t)a0; outv[1] = (half_t)a1; outv[2] = (half_t)a2; outv[3] = (half_t)a3;
  *(half4_t*)&Mt[((size_t)h * 256 + et * 32 + e) * 256 + dt * 32 + dg * 4] = outv;
}

// ---------------- transpose v/w1/w2 -> f16 [n][d] ----------------
__global__ __launch_bounds__(256) void prepT_kernel(const float* __restrict__ v,
                                                    const float* __restrict__ w1,
                                                    const float* __restrict__ w2,
                                                    half_t* vt, half_t* w1t, half_t* w2t) {
  int which = blockIdx.x >> 8, n = blockIdx.x & 255, d = threadIdx.x;
  const float* src = which == 0 ? v : (which == 1 ? w1 : w2);
  half_t* dst = which == 0 ? vt : (which == 1 ? w1t : w2t);
  dst[(size_t)n * 256 + d] = (half_t)src[(size_t)d * 256 + n];
}

// ---------------- LN1 + blocked permute -> f16; one wave per row ----------------
__global__ __launch_bounds__(256) void ln1_kernel(
    const float* __restrict__ x, const float* __restrict__ w,
    const float* __restrict__ bia, half_t* __restrict__ aH) {
  int row  = blockIdx.x * 4 + (threadIdx.x >> 6);
  int lane = threadIdx.x & 63;
  float4 v = *(const float4*)&x[(size_t)row * 256 + lane * 4];
  float s  = v.x + v.y + v.z + v.w;
  float sq = v.x * v.x + v.y * v.y + v.z * v.z + v.w * v.w;
  #pragma unroll
  for (int off = 1; off < 64; off <<= 1) { s += __shfl_xor(s, off); sq += __shfl_xor(sq, off); }
  float mean = s * (1.f / 256), var = sq * (1.f / 256) - mean * mean;
  float r = rsqrtf(var + EPSc);
  float4 wv = *(const float4*)&w[lane * 4];
  float4 bv = *(const float4*)&bia[lane * 4];
  half4_t y;
  y[0] = (half_t)((v.x - mean) * r * wv.x + bv.x);
  y[1] = (half_t)((v.y - mean) * r * wv.y + bv.y);
  y[2] = (half_t)((v.z - mean) * r * wv.z + bv.z);
  y[3] = (half_t)((v.w - mean) * r * wv.w + bv.w);
  int bb = row >> 12, p = row & 4095, hh = p >> 6, ww = p & 63;
  int m = (hh & 7) * 8 + (ww & 7), n = (hh >> 3) * 8 + (ww >> 3);
  *(half4_t*)&aH[((size_t)((bb * 64 + m) * 64 + n)) * 256 + lane * 4] = y;
}

// ---------------- tiled GEMM: C(128x128 tile) = A(Mx256) @ Bt(Nx256)^T, K=256 ----------------
// epi 1: +bias relu -> f16. epi 2: +bias, outf += (resid).   (epi 0 path retained)
__global__ __launch_bounds__(256) void wgemm_kernel(
    const half_t* __restrict__ A, const half_t* __restrict__ Bt,
    const float* __restrict__ bias, float* __restrict__ outf,
    half_t* __restrict__ outh, int epi, int ldn, int mtiles) {
  __shared__ half_t shA[128 * 72];   // 18 KB, stride 72: 16B-aligned rows, conflict-free
  __shared__ half_t shB[128 * 72];
  int tid = threadIdx.x, lane = tid & 63, wave = tid >> 6;
  int l16 = lane & 15, quad = lane >> 4;
  int mtile = blockIdx.x % mtiles, ntile = blockIdx.x / mtiles;
  int r0 = mtile * 128, n0 = ntile * 128;
  int wm = (wave >> 1) * 64, wn = (wave & 1) * 64;
  f32x4 acc[4][4];
  #pragma unroll
  for (int mt = 0; mt < 4; mt++)
    #pragma unroll
    for (int nt = 0; nt < 4; nt++) acc[mt][nt] = (f32x4){0.f, 0.f, 0.f, 0.f};
  for (int kb = 0; kb < 256; kb += 64) {
    if (kb) __syncthreads();
    #pragma unroll
    for (int rr = 0; rr < 4; rr++) {
      int idx = rr * 256 + tid;
      int row = idx >> 3, c8 = (idx & 7) * 8;
      *(frag8*)&shA[row * 72 + c8] = *(const frag8*)&A[(size_t)(r0 + row) * 256 + kb + c8];
      *(frag8*)&shB[row * 72 + c8] = *(const frag8*)&Bt[(size_t)(n0 + row) * 256 + kb + c8];
    }
    __syncthreads();
    #pragma unroll
    for (int kh = 0; kh < 2; kh++) {
      int ko = kh * 32 + quad * 8;
      frag8 af[4], bf[4];
      #pragma unroll
      for (int mt = 0; mt < 4; mt++) af[mt] = *(const frag8*)&shA[(wm + mt * 16 + l16) * 72 + ko];
      #pragma unroll
      for (int nt = 0; nt < 4; nt++) bf[nt] = *(const frag8*)&shB[(wn + nt * 16 + l16) * 72 + ko];
      #pragma unroll
      for (int mt = 0; mt < 4; mt++)
        #pragma unroll
        for (int nt = 0; nt < 4; nt++) acc[mt][nt] = MFMA_F16(af[mt], bf[nt], acc[mt][nt]);
    }
  }
  #pragma unroll
  for (int mt = 0; mt < 4; mt++)
    #pragma unroll
    for (int nt = 0; nt < 4; nt++)
      #pragma unroll
      for (int r = 0; r < 4; r++) {
        int row = r0 + wm + mt * 16 + quad * 4 + r;
        int col = n0 + wn + nt * 16 + l16;
        float vv = acc[mt][nt][r];
        if (epi) vv += bias[col];
        if (epi == 1) vv = fmaxf(vv, 0.f);
        size_t idx = (size_t)row * ldn + col;
        if (epi == 2) outf[idx] = vv + outf[idx];
        else          outh[idx] = (half_t)vv;
      }
}

// ---------------- fully fused attention: W + score + softmax + PV, 4 heads per block ----------------
// One 512-thread block per (mode, b, slice). 8 waves. LDS 78 KB -> 2 blocks/CU.
// Grid 1024: g<512 -> mode 0 (group (b, n=slice), heads 0-3, Z0); g>=512 -> mode 1 (heads 4-7, Z1).
// W computed in e-QUARTERS into union W/P buffer; S accumulated in registers across quarters
// (identical fp32 summation order to the full-W version -> bitwise identical output).
__global__ __launch_bounds__(512, 4) void attn_kernel(
    const half_t* __restrict__ aH, const half_t* __restrict__ Mt,
    const half_t* __restrict__ vt, const float* __restrict__ osum,
    half_t* __restrict__ Z0, half_t* __restrict__ Z1) {
  __shared__ half_t shA[64 * 264];   // A_g[z][d], 33.0 KB
  __shared__ half_t shVT[256 * 72];  // VT_g[vout][z], 36.0 KB
  __shared__ half_t shWP[64 * 72];   // union: W e-quarter [64 m][64 e] / P[64 m][64 z], 9.0 KB
  int tid = threadIdx.x, lane = tid & 63, w = tid >> 6;
  int l16 = lane & 15, quad = lane >> 4;
  int g = blockIdx.x;
  int mode = g >> 9, gg = g & 511, b = gg >> 6, slice = gg & 63;
  int hbase = mode * 4;
  half_t* Z = mode ? Z1 : Z0;

  // --- stage A_g (64x256 f16 = 32 KB), coalesced ---
  #pragma unroll
  for (int i = 0; i < 4; i++) {
    int slot = i * 512 + tid;
    int z = slot >> 5, c8 = (slot & 31) * 8;
    size_t rz = mode ? ((size_t)(b * 64 + slice) * 64 + z) : ((size_t)(b * 64 + z) * 64 + slice);
    *(frag8*)&shA[z * 264 + c8] = *(const frag8*)&aH[rz * 256 + c8];
  }
  __syncthreads();

  // --- vtrans: VT_g[vout][z] = sum_d v[d][vout] A_g[z][d]; wave w owns vout in [w*32, w*32+32) ---
  {
    f32x4 vacc[2][4];
    #pragma unroll
    for (int dt = 0; dt < 2; dt++)
      #pragma unroll
      for (int zt = 0; zt < 4; zt++) vacc[dt][zt] = (f32x4){0.f, 0.f, 0.f, 0.f};
    for (int ks = 0; ks < 8; ks++) {
      int k0 = ks * 32 + quad * 8;
      frag8 afr[2], bfr[4];
      #pragma unroll
      for (int dt = 0; dt < 2; dt++)
        afr[dt] = *(const frag8*)&vt[(size_t)(w * 32 + dt * 16 + l16) * 256 + k0];
      #pragma unroll
      for (int zt = 0; zt < 4; zt++)
        bfr[zt] = *(const frag8*)&shA[(zt * 16 + l16) * 264 + k0];
      #pragma unroll
      for (int dt = 0; dt < 2; dt++)
        #pragma unroll
        for (int zt = 0; zt < 4; zt++) vacc[dt][zt] = MFMA_F16(afr[dt], bfr[zt], vacc[dt][zt]);
    }
    #pragma unroll
    for (int dt = 0; dt < 2; dt++)
      #pragma unroll
      for (int zt = 0; zt < 4; zt++)
        #pragma unroll
        for (int r = 0; r < 4; r++)
          shVT[(w * 32 + dt * 16 + quad * 4 + r) * 72 + zt * 16 + l16] = (half_t)vacc[dt][zt][r];
  }

  // preload os[h][d] for this wave's d-slice
  float osv[4][2];
  #pragma unroll
  for (int hh = 0; hh < 4; hh++)
    #pragma unroll
    for (int dt = 0; dt < 2; dt++)
      osv[hh][dt] = osum[(hbase + hh) * 256 + w * 32 + dt * 16 + l16];

  f32x4 zacc[4][2];   // fp32 Z accumulator: [m-frag][d-sub], d = w*32 + dt*16 + l16
  #pragma unroll
  for (int mf = 0; mf < 4; mf++)
    #pragma unroll
    for (int dt = 0; dt < 2; dt++) zacc[mf][dt] = (f32x4){0.f, 0.f, 0.f, 0.f};
  __syncthreads();   // shVT ready

  int mfw = w & 3, ehw = w >> 2;   // W-step: wave owns (m-tile mfw, e-32-half ehw) of each quarter
  for (int hh = 0; hh < 4; hh++) {
    const half_t* Mth = Mt + (size_t)(hbase + hh) * 65536;
    f32x4 sacc[4];
    #pragma unroll
    for (int zt = 0; zt < 4; zt++) sacc[zt] = (f32x4){0.f, 0.f, 0.f, 0.f};
    for (int q = 0; q < 4; q++) {
      // --- W quarter: W[m][e_loc] = sum_d A_g[m][d] Mt_h[q*64+e_loc][d], e_loc in [0,64) ---
      f32x4 wacc[2];
      wacc[0] = (f32x4){0.f, 0.f, 0.f, 0.f};
      wacc[1] = (f32x4){0.f, 0.f, 0.f, 0.f};
      for (int ks = 0; ks < 8; ks++) {
        int k0 = ks * 32 + quad * 8;
        frag8 af = *(const frag8*)&shA[(mfw * 16 + l16) * 264 + k0];
        #pragma unroll
        for (int et = 0; et < 2; et++) {
          frag8 bf = *(const frag8*)&Mth[(size_t)(q * 64 + ehw * 32 + et * 16 + l16) * 256 + k0];
          wacc[et] = MFMA_F16(af, bf, wacc[et]);
        }
      }
      #pragma unroll
      for (int et = 0; et < 2; et++)
        #pragma unroll
        for (int r = 0; r < 4; r++)
          shWP[(mfw * 16 + quad * 4 + r) * 72 + ehw * 32 + et * 16 + l16] = (half_t)wacc[et][r];
      __syncthreads();
      // --- S partial: sacc += W_q @ A_g[:, q*64:q*64+64]^T ; waves 0-3, m = w*16 + l16 ---
      if (w < 4) {
        #pragma unroll
        for (int ks2 = 0; ks2 < 2; ks2++) {
          int kq = ks2 * 32 + quad * 8;
          frag8 wf = *(const frag8*)&shWP[(w * 16 + l16) * 72 + kq];
          #pragma unroll
          for (int zt = 0; zt < 4; zt++) {
            frag8 kf = *(const frag8*)&shA[(zt * 16 + l16) * 264 + q * 64 + kq];
            sacc[zt] = MFMA_F16(wf, kf, sacc[zt]);
          }
        }
      }
      if (q < 3) __syncthreads();   // shWP reused by next quarter
    }
    // --- softmax rows m = w*16 + quad*4 + r over 64 z; P -> shWP (W quarter dead) ---
    if (w < 4) {
      #pragma unroll
      for (int r = 0; r < 4; r++) {
        float mx = fmaxf(fmaxf(sacc[0][r], sacc[1][r]), fmaxf(sacc[2][r], sacc[3][r]));
        #pragma unroll
        for (int off = 1; off < 16; off <<= 1) mx = fmaxf(mx, __shfl_xor(mx, off));
        float e0 = __expf(sacc[0][r] - mx), e1 = __expf(sacc[1][r] - mx);
        float e2 = __expf(sacc[2][r] - mx), e3 = __expf(sacc[3][r] - mx);
        float sum = e0 + e1 + e2 + e3;
        #pragma unroll
        for (int off = 1; off < 16; off <<= 1) sum += __shfl_xor(sum, off);
        float inv = 1.f / sum;
        int m = w * 16 + quad * 4 + r;
        shWP[m * 72 + l16 +  0] = (half_t)(e0 * inv);
        shWP[m * 72 + l16 + 16] = (half_t)(e1 * inv);
        shWP[m * 72 + l16 + 32] = (half_t)(e2 * inv);
        shWP[m * 72 + l16 + 48] = (half_t)(e3 * inv);
      }
    }
    __syncthreads();
    // --- PV: O[m][vout] = P @ VT^T; zacc += O * os[h]; wave w owns vout slice [w*32, +32) ---
    {
      frag8 pf[4][2];
      #pragma unroll
      for (int mf = 0; mf < 4; mf++)
        #pragma unroll
        for (int ks = 0; ks < 2; ks++)
          pf[mf][ks] = *(const frag8*)&shWP[(mf * 16 + l16) * 72 + ks * 32 + quad * 8];
      #pragma unroll
      for (int dt = 0; dt < 2; dt++) {
        frag8 vf0 = *(const frag8*)&shVT[(w * 32 + dt * 16 + l16) * 72 +  0 + quad * 8];
        frag8 vf1 = *(const frag8*)&shVT[(w * 32 + dt * 16 + l16) * 72 + 32 + quad * 8];
        #pragma unroll
        for (int mf = 0; mf < 4; mf++) {
          f32x4 oacc = (f32x4){0.f, 0.f, 0.f, 0.f};
          oacc = MFMA_F16(pf[mf][0], vf0, oacc);
          oacc = MFMA_F16(pf[mf][1], vf1, oacc);
          #pragma unroll
          for (int r = 0; r < 4; r++) zacc[mf][dt][r] += oacc[r] * osv[hh][dt];
        }
      }
    }
    __syncthreads();   // shWP/shVT reuse next head; also gates final shA overwrite
  }

  // --- Z writeback: stage f16 into shA (dead), then coalesced 16B stores (blocked layout) ---
  #pragma unroll
  for (int mf = 0; mf < 4; mf++)
    #pragma unroll
    for (int dt = 0; dt < 2; dt++)
      #pragma unroll
      for (int r = 0; r < 4; r++)
        shA[(mf * 16 + quad * 4 + r) * 264 + w * 32 + dt * 16 + l16] = (half_t)zacc[mf][dt][r];
  __syncthreads();
  #pragma unroll
  for (int i = 0; i < 4; i++) {
    int slot = i * 512 + tid;
    int grow = slot >> 5, c8 = (slot & 31) * 8;
    size_t zrow = mode ? ((size_t)(b * 64 + slice) * 64 + grow) : ((size_t)(b * 64 + grow) * 64 + slice);
    *(frag8*)&Z[zrow * 256 + c8] = *(const frag8*)&shA[grow * 264 + c8];
  }
}

// ---------------- residual + LN2; x2 -> d_out fp32, h -> f16 (Z = Z0 + Z1, BLOCKED layout) ----------------
__global__ __launch_bounds__(256) void ln2_kernel(
    const float* __restrict__ x, const half_t* __restrict__ Z0, const half_t* __restrict__ Z1,
    const float* __restrict__ w, const float* __restrict__ bia,
    float* __restrict__ x2out, half_t* __restrict__ hH) {
  int row  = blockIdx.x * 4 + (threadIdx.x >> 6);
  int lane = threadIdx.x & 63;
  size_t base = (size_t)row * 256 + lane * 4;
  int bb = row >> 12, p = row & 4095, hh = p >> 6, ww = p & 63;
  int m = (hh & 7) * 8 + (ww & 7), n = (hh >> 3) * 8 + (ww >> 3);
  size_t zbase = ((size_t)((bb * 64 + m) * 64 + n)) * 256 + lane * 4;
  float4 xv = *(const float4*)&x[base];
  half4_t zv0 = *(const half4_t*)&Z0[zbase];
  half4_t zv1 = *(const half4_t*)&Z1[zbase];
  float4 v;
  v.x = xv.x + (float)zv0[0] + (float)zv1[0];
  v.y = xv.y + (float)zv0[1] + (float)zv1[1];
  v.z = xv.z + (float)zv0[2] + (float)zv1[2];
  v.w = xv.w + (float)zv0[3] + (float)zv1[3];
  float s  = v.x + v.y + v.z + v.w;
  float sq = v.x * v.x + v.y * v.y + v.z * v.z + v.w * v.w;
  #pragma unroll
  for (int off = 1; off < 64; off <<= 1) { s += __shfl_xor(s, off); sq += __shfl_xor(sq, off); }
  float mean = s * (1.f / 256), var = sq * (1.f / 256) - mean * mean;
  float r = rsqrtf(var + EPSc);
  float4 wv = *(const float4*)&w[lane * 4];
  float4 bv = *(const float4*)&bia[lane * 4];
  *(float4*)&x2out[base] = v;
  half4_t y;
  y[0] = (half_t)((v.x - mean) * r * wv.x + bv.x);
  y[1] = (half_t)((v.y - mean) * r * wv.y + bv.y);
  y[2] = (half_t)((v.z - mean) * r * wv.z + bv.z);
  y[3] = (half_t)((v.w - mean) * r * wv.w + bv.w);
  *(half4_t*)&hH[base] = y;
}

extern "C" void kernel_launch(void* const* d_in, const int* in_sizes, int n_in,
                              void* d_out, int out_size, void* d_ws, size_t ws_size,
                              hipStream_t stream) {
  (void)in_sizes; (void)n_in; (void)out_size; (void)ws_size;
  const float* x    = (const float*)d_in[0];
  const float* ln1w = (const float*)d_in[1];
  const float* ln1b = (const float*)d_in[2];
  const float* q    = (const float*)d_in[3];
  const float* k    = (const float*)d_in[4];
  const float* v    = (const float*)d_in[5];
  const float* o    = (const float*)d_in[6];
  const float* ln2w = (const float*)d_in[7];
  const float* ln2b = (const float*)d_in[8];
  const float* w1   = (const float*)d_in[9];
  const float* b1   = (const float*)d_in[10];
  const float* w2   = (const float*)d_in[11];
  const float* b2   = (const float*)d_in[12];
  float* out = (float*)d_out;

  const size_t ROWS = (size_t)Bc * Tc;        // 32768
  const size_t ELTS = ROWS * Dc;              // 8,388,608
  const size_t MB16 = ELTS * sizeof(half_t);  // 16 MiB
  // ws plan (50 MiB used; 82 MiB verified safe in r7):
  //   [0:8K) os | [64K:1M+64K) Mt [h][e][d] | +1M: vt/w1t/w2t (128K each)
  //   [2M:18M)   aH f16 (blocked)  -> reused as hH after attention
  //   [18M:34M)  Z0 f16 (BLOCKED, heads 0-3)
  //   [34M:50M)  Z1 f16 (BLOCKED, heads 4-7) -> reused as tH after ln2
  char* ws = (char*)d_ws;
  float*  osumB = (float*)ws;
  half_t* Mt    = (half_t*)(ws + (64 << 10));
  half_t* vt    = (half_t*)(ws + (64 << 10) + (1 << 20));
  half_t* w1t   = (half_t*)(ws + (64 << 10) + (1 << 20) + (128 << 10));
  half_t* w2t   = (half_t*)(ws + (64 << 10) + (1 << 20) + (256 << 10));
  half_t* aH    = (half_t*)(ws + (2 << 20));
  half_t* Zb0   = (half_t*)(ws + (2 << 20) + MB16);
  half_t* Zb1   = (half_t*)(ws + (2 << 20) + 2 * MB16);
  half_t* hH    = aH;   // reuse (a dead after attention)
  half_t* tH    = Zb1;  // reuse (Z1 dead after ln2)

  osum_kernel <<<8,   256, 0, stream>>>(o, osumB);
  prepM_kernel<<<512, 256, 0, stream>>>(q, k, Mt);
  prepT_kernel<<<768, 256, 0, stream>>>(v, w1, w2, vt, w1t, w2t);
  ln1_kernel  <<<ROWS / 4, 256, 0, stream>>>(x, ln1w, ln1b, aH);
  // fused attention: ONE dispatch, 1024 blocks (512 mode-0 -> Z0, 512 mode-1 -> Z1), 2 blocks/CU
  attn_kernel <<<1024, 512, 0, stream>>>(aH, Mt, vt, osumB, Zb0, Zb1);
  // residual + LN2 (sums Z0+Z1 in fp32)
  ln2_kernel  <<<ROWS / 4, 256, 0, stream>>>(x, Zb0, Zb1, ln2w, ln2b, out, hH);
  // MLP on the tiled GEMM: fc1 relu -> tH; fc2 +bias +resid -> out
  wgemm_kernel<<<512, 256, 0, stream>>>(hH, w1t, b1, nullptr, tH, 1, 256, 256);
  wgemm_kernel<<<512, 256, 0, stream>>>(tH, w2t, b2, out, nullptr, 2, 256, 256);
}

// Round 4
// 510.699 us; speedup vs baseline: 1.1374x; 1.1374x over previous
//
#include <hip/hip_runtime.h>

// (B, N, D, H) = (8, 4096, 256, 8), PS=8 -> image 64x64; blocked m=fine pos, n=tile idx.
// SPEC FACT 1: no softmax temperature; logit sigma ~16. f16 inputs + fp32 MFMA acc -> logit err ~0.01 (safe).
// SPEC FACT 2: Z = einsum('bhmnd,hdv->bmnd', O, o) is DIAGONAL in d, SUMS v:
//   Z[...,d] = sum_h O_h[...,d] * os[h][d], os[h][d] = sum_v o[h,d,v].
// SPEC FACT 3: S = (A M_h) A_g^T with M_h = q_h k^T. W = A·M_h computed IN-BLOCK in e-QUARTERS
//   (64x64 W sub-tile in a union W/P buffer) -> LDS 78 KB (2 blocks/CU possible).
// REGISTER LESSON (r3): __launch_bounds__(512,4) clamped arch VGPRs to 64 -> ~550 MB scratch
//   spill traffic, 507 us. (512,2) compiles this shape to 128 VGPR, zero spill. DO NOT TIGHTEN.
// MFMA conventions (verified r6/r7, absmax 0.125): mfma_f32_16x16x32_f16 computes C = A @ B^T:
//   A-frag: A[m = l16][k = quad*8 + j]; B-frag same over n-rows; C/D: col = l16, row = quad*4 + reg.
// Z kept in BLOCKED layout, TWO buffers (mode0 heads 0-3, mode1 heads 4-7); ln2 sums them in fp32.
#define Bc   8
#define Tc   4096
#define Dc   256
#define EPSc 1e-5f

typedef _Float16 half_t;
typedef __attribute__((ext_vector_type(4))) _Float16 half4_t;
typedef __attribute__((ext_vector_type(8))) _Float16 frag8;
typedef __attribute__((ext_vector_type(4))) float f32x4;

#define MFMA_F16(a, b, c) __builtin_amdgcn_mfma_f32_16x16x32_f16((a), (b), (c), 0, 0, 0)

// ---------------- os[h][d] = sum_v o[h,d,v] ----------------
__global__ __launch_bounds__(256) void osum_kernel(const float* __restrict__ o, float* __restrict__ os) {
  int h = blockIdx.x, d = threadIdx.x;
  const float* row = o + ((size_t)h * 256 + d) * 256;
  float s = 0.f;
  #pragma unroll 8
  for (int v = 0; v < 256; v += 4) {
    float4 r4 = *(const float4*)&row[v];
    s += r4.x + r4.y + r4.z + r4.w;
  }
  os[h * 256 + d] = s;
}

// ---------------- Mt[h][e][d] = M_h[d][e] = sum_i q[h][d][i]*k[e][i]  (f16) ----------------
// Tiled fp32 GEMM: 512 blocks = h(8) x etile(8) x dtile(8); 32x32 output tile per block.
__global__ __launch_bounds__(256) void prepM_kernel(const float* __restrict__ q,
                                                    const float* __restrict__ k,
                                                    half_t* __restrict__ Mt) {
  __shared__ float shK[32 * 260];   // 32.5 KB
  __shared__ float shQ[32 * 260];   // 32.5 KB  (65 KB total -> 2 blocks/CU)
  int tid = threadIdx.x;
  int h = blockIdx.x >> 6, et = (blockIdx.x >> 3) & 7, dt = blockIdx.x & 7;
  const float* kbase = k + (size_t)(et * 32) * 256;
  const float* qbase = q + ((size_t)h * 256 + dt * 32) * 256;
  #pragma unroll
  for (int r = 0; r < 8; r++) {
    int f = r * 256 + tid;                  // float4 slot 0..2047; one row per wave
    int row = f >> 6, c4 = (f & 63) * 4;
    *(float4*)&shK[row * 260 + c4] = *(const float4*)&kbase[(size_t)row * 256 + c4];
    *(float4*)&shQ[row * 260 + c4] = *(const float4*)&qbase[(size_t)row * 256 + c4];
  }
  __syncthreads();
  int e = tid & 31, dg = tid >> 5;          // thread -> (e, 4 consecutive d)
  const float* kr = &shK[e * 260];
  const float* q0 = &shQ[(dg * 4 + 0) * 260];
  const float* q1 = &shQ[(dg * 4 + 1) * 260];
  const float* q2 = &shQ[(dg * 4 + 2) * 260];
  const float* q3 = &shQ[(dg * 4 + 3) * 260];
  float a0 = 0.f, a1 = 0.f, a2 = 0.f, a3 = 0.f;
  #pragma unroll 4
  for (int kk = 0; kk < 256; kk += 4) {
    float4 kv = *(const float4*)&kr[kk];
    float4 v0 = *(const float4*)&q0[kk];
    float4 v1 = *(const float4*)&q1[kk];
    float4 v2 = *(const float4*)&q2[kk];
    float4 v3 = *(const float4*)&q3[kk];
    a0 += v0.x * kv.x + v0.y * kv.y + v0.z * kv.z + v0.w * kv.w;
    a1 += v1.x * kv.x + v1.y * kv.y + v1.z * kv.z + v1.w * kv.w;
    a2 += v2.x * kv.x + v2.y * kv.y + v2.z * kv.z + v2.w * kv.w;
    a3 += v3.x * kv.x + v3.y * kv.y + v3.z * kv.z + v3.w * kv.w;
  }
  half4_t outv;
  outv[0] = (half_t)a0; outv[1] = (half_t)a1; outv[2] = (half_t)a2; outv[3] = (half_t)a3;
  *(half4_t*)&Mt[((size_t)h * 256 + et * 32 + e) * 256 + dt * 32 + dg * 4] = outv;
}

// ---------------- transpose v/w1/w2 -> f16 [n][d] ----------------
__global__ __launch_bounds__(256) void prepT_kernel(const float* __restrict__ v,
                                                    const float* __restrict__ w1,
                                                    const float* __restrict__ w2,
                                                    half_t* vt, half_t* w1t, half_t* w2t) {
  int which = blockIdx.x >> 8, n = blockIdx.x & 255, d = threadIdx.x;
  const float* src = which == 0 ? v : (which == 1 ? w1 : w2);
  half_t* dst = which == 0 ? vt : (which == 1 ? w1t : w2t);
  dst[(size_t)n * 256 + d] = (half_t)src[(size_t)d * 256 + n];
}

// ---------------- LN1 + blocked permute -> f16; one wave per row ----------------
__global__ __launch_bounds__(256) void ln1_kernel(
    const float* __restrict__ x, const float* __restrict__ w,
    const float* __restrict__ bia, half_t* __restrict__ aH) {
  int row  = blockIdx.x * 4 + (threadIdx.x >> 6);
  int lane = threadIdx.x & 63;
  float4 v = *(const float4*)&x[(size_t)row * 256 + lane * 4];
  float s  = v.x + v.y + v.z + v.w;
  float sq = v.x * v.x + v.y * v.y + v.z * v.z + v.w * v.w;
  #pragma unroll
  for (int off = 1; off < 64; off <<= 1) { s += __shfl_xor(s, off); sq += __shfl_xor(sq, off); }
  float mean = s * (1.f / 256), var = sq * (1.f / 256) - mean * mean;
  float r = rsqrtf(var + EPSc);
  float4 wv = *(const float4*)&w[lane * 4];
  float4 bv = *(const float4*)&bia[lane * 4];
  half4_t y;
  y[0] = (half_t)((v.x - mean) * r * wv.x + bv.x);
  y[1] = (half_t)((v.y - mean) * r * wv.y + bv.y);
  y[2] = (half_t)((v.z - mean) * r * wv.z + bv.z);
  y[3] = (half_t)((v.w - mean) * r * wv.w + bv.w);
  int bb = row >> 12, p = row & 4095, hh = p >> 6, ww = p & 63;
  int m = (hh & 7) * 8 + (ww & 7), n = (hh >> 3) * 8 + (ww >> 3);
  *(half4_t*)&aH[((size_t)((bb * 64 + m) * 64 + n)) * 256 + lane * 4] = y;
}

// ---------------- tiled GEMM: C(128x128 tile) = A(Mx256) @ Bt(Nx256)^T, K=256 ----------------
// epi 1: +bias relu -> f16. epi 2: +bias, outf += (resid).   (epi 0 path retained)
__global__ __launch_bounds__(256) void wgemm_kernel(
    const half_t* __restrict__ A, const half_t* __restrict__ Bt,
    const float* __restrict__ bias, float* __restrict__ outf,
    half_t* __restrict__ outh, int epi, int ldn, int mtiles) {
  __shared__ half_t shA[128 * 72];   // 18 KB, stride 72: 16B-aligned rows, conflict-free
  __shared__ half_t shB[128 * 72];
  int tid = threadIdx.x, lane = tid & 63, wave = tid >> 6;
  int l16 = lane & 15, quad = lane >> 4;
  int mtile = blockIdx.x % mtiles, ntile = blockIdx.x / mtiles;
  int r0 = mtile * 128, n0 = ntile * 128;
  int wm = (wave >> 1) * 64, wn = (wave & 1) * 64;
  f32x4 acc[4][4];
  #pragma unroll
  for (int mt = 0; mt < 4; mt++)
    #pragma unroll
    for (int nt = 0; nt < 4; nt++) acc[mt][nt] = (f32x4){0.f, 0.f, 0.f, 0.f};
  for (int kb = 0; kb < 256; kb += 64) {
    if (kb) __syncthreads();
    #pragma unroll
    for (int rr = 0; rr < 4; rr++) {
      int idx = rr * 256 + tid;
      int row = idx >> 3, c8 = (idx & 7) * 8;
      *(frag8*)&shA[row * 72 + c8] = *(const frag8*)&A[(size_t)(r0 + row) * 256 + kb + c8];
      *(frag8*)&shB[row * 72 + c8] = *(const frag8*)&Bt[(size_t)(n0 + row) * 256 + kb + c8];
    }
    __syncthreads();
    #pragma unroll
    for (int kh = 0; kh < 2; kh++) {
      int ko = kh * 32 + quad * 8;
      frag8 af[4], bf[4];
      #pragma unroll
      for (int mt = 0; mt < 4; mt++) af[mt] = *(const frag8*)&shA[(wm + mt * 16 + l16) * 72 + ko];
      #pragma unroll
      for (int nt = 0; nt < 4; nt++) bf[nt] = *(const frag8*)&shB[(wn + nt * 16 + l16) * 72 + ko];
      #pragma unroll
      for (int mt = 0; mt < 4; mt++)
        #pragma unroll
        for (int nt = 0; nt < 4; nt++) acc[mt][nt] = MFMA_F16(af[mt], bf[nt], acc[mt][nt]);
    }
  }
  #pragma unroll
  for (int mt = 0; mt < 4; mt++)
    #pragma unroll
    for (int nt = 0; nt < 4; nt++)
      #pragma unroll
      for (int r = 0; r < 4; r++) {
        int row = r0 + wm + mt * 16 + quad * 4 + r;
        int col = n0 + wn + nt * 16 + l16;
        float vv = acc[mt][nt][r];
        if (epi) vv += bias[col];
        if (epi == 1) vv = fmaxf(vv, 0.f);
        size_t idx = (size_t)row * ldn + col;
        if (epi == 2) outf[idx] = vv + outf[idx];
        else          outh[idx] = (half_t)vv;
      }
}

// ---------------- fully fused attention: W + score + softmax + PV, 4 heads per block ----------------
// One 512-thread block per (mode, b, slice). 8 waves. LDS 78 KB.
// Grid 1024: g<512 -> mode 0 (group (b, n=slice), heads 0-3, Z0); g>=512 -> mode 1 (heads 4-7, Z1).
// W computed in e-QUARTERS into union W/P buffer; S accumulated in registers across quarters
// (identical fp32 summation order to the full-W version -> bitwise identical output).
__global__ __launch_bounds__(512, 2) void attn_kernel(
    const half_t* __restrict__ aH, const half_t* __restrict__ Mt,
    const half_t* __restrict__ vt, const float* __restrict__ osum,
    half_t* __restrict__ Z0, half_t* __restrict__ Z1) {
  __shared__ half_t shA[64 * 264];   // A_g[z][d], 33.0 KB
  __shared__ half_t shVT[256 * 72];  // VT_g[vout][z], 36.0 KB
  __shared__ half_t shWP[64 * 72];   // union: W e-quarter [64 m][64 e] / P[64 m][64 z], 9.0 KB
  int tid = threadIdx.x, lane = tid & 63, w = tid >> 6;
  int l16 = lane & 15, quad = lane >> 4;
  int g = blockIdx.x;
  int mode = g >> 9, gg = g & 511, b = gg >> 6, slice = gg & 63;
  int hbase = mode * 4;
  half_t* Z = mode ? Z1 : Z0;

  // --- stage A_g (64x256 f16 = 32 KB), coalesced ---
  #pragma unroll
  for (int i = 0; i < 4; i++) {
    int slot = i * 512 + tid;
    int z = slot >> 5, c8 = (slot & 31) * 8;
    size_t rz = mode ? ((size_t)(b * 64 + slice) * 64 + z) : ((size_t)(b * 64 + z) * 64 + slice);
    *(frag8*)&shA[z * 264 + c8] = *(const frag8*)&aH[rz * 256 + c8];
  }
  __syncthreads();

  // --- vtrans: VT_g[vout][z] = sum_d v[d][vout] A_g[z][d]; wave w owns vout in [w*32, w*32+32) ---
  {
    f32x4 vacc[2][4];
    #pragma unroll
    for (int dt = 0; dt < 2; dt++)
      #pragma unroll
      for (int zt = 0; zt < 4; zt++) vacc[dt][zt] = (f32x4){0.f, 0.f, 0.f, 0.f};
    for (int ks = 0; ks < 8; ks++) {
      int k0 = ks * 32 + quad * 8;
      frag8 afr[2], bfr[4];
      #pragma unroll
      for (int dt = 0; dt < 2; dt++)
        afr[dt] = *(const frag8*)&vt[(size_t)(w * 32 + dt * 16 + l16) * 256 + k0];
      #pragma unroll
      for (int zt = 0; zt < 4; zt++)
        bfr[zt] = *(const frag8*)&shA[(zt * 16 + l16) * 264 + k0];
      #pragma unroll
      for (int dt = 0; dt < 2; dt++)
        #pragma unroll
        for (int zt = 0; zt < 4; zt++) vacc[dt][zt] = MFMA_F16(afr[dt], bfr[zt], vacc[dt][zt]);
    }
    #pragma unroll
    for (int dt = 0; dt < 2; dt++)
      #pragma unroll
      for (int zt = 0; zt < 4; zt++)
        #pragma unroll
        for (int r = 0; r < 4; r++)
          shVT[(w * 32 + dt * 16 + quad * 4 + r) * 72 + zt * 16 + l16] = (half_t)vacc[dt][zt][r];
  }

  // preload os[h][d] for this wave's d-slice
  float osv[4][2];
  #pragma unroll
  for (int hh = 0; hh < 4; hh++)
    #pragma unroll
    for (int dt = 0; dt < 2; dt++)
      osv[hh][dt] = osum[(hbase + hh) * 256 + w * 32 + dt * 16 + l16];

  f32x4 zacc[4][2];   // fp32 Z accumulator: [m-frag][d-sub], d = w*32 + dt*16 + l16
  #pragma unroll
  for (int mf = 0; mf < 4; mf++)
    #pragma unroll
    for (int dt = 0; dt < 2; dt++) zacc[mf][dt] = (f32x4){0.f, 0.f, 0.f, 0.f};
  __syncthreads();   // shVT ready

  int mfw = w & 3, ehw = w >> 2;   // W-step: wave owns (m-tile mfw, e-32-half ehw) of each quarter
  for (int hh = 0; hh < 4; hh++) {
    const half_t* Mth = Mt + (size_t)(hbase + hh) * 65536;
    f32x4 sacc[4];
    #pragma unroll
    for (int zt = 0; zt < 4; zt++) sacc[zt] = (f32x4){0.f, 0.f, 0.f, 0.f};
    for (int q = 0; q < 4; q++) {
      // --- W quarter: W[m][e_loc] = sum_d A_g[m][d] Mt_h[q*64+e_loc][d], e_loc in [0,64) ---
      f32x4 wacc[2];
      wacc[0] = (f32x4){0.f, 0.f, 0.f, 0.f};
      wacc[1] = (f32x4){0.f, 0.f, 0.f, 0.f};
      for (int ks = 0; ks < 8; ks++) {
        int k0 = ks * 32 + quad * 8;
        frag8 af = *(const frag8*)&shA[(mfw * 16 + l16) * 264 + k0];
        #pragma unroll
        for (int et = 0; et < 2; et++) {
          frag8 bf = *(const frag8*)&Mth[(size_t)(q * 64 + ehw * 32 + et * 16 + l16) * 256 + k0];
          wacc[et] = MFMA_F16(af, bf, wacc[et]);
        }
      }
      #pragma unroll
      for (int et = 0; et < 2; et++)
        #pragma unroll
        for (int r = 0; r < 4; r++)
          shWP[(mfw * 16 + quad * 4 + r) * 72 + ehw * 32 + et * 16 + l16] = (half_t)wacc[et][r];
      __syncthreads();
      // --- S partial: sacc += W_q @ A_g[:, q*64:q*64+64]^T ; waves 0-3, m = w*16 + l16 ---
      if (w < 4) {
        #pragma unroll
        for (int ks2 = 0; ks2 < 2; ks2++) {
          int kq = ks2 * 32 + quad * 8;
          frag8 wf = *(const frag8*)&shWP[(w * 16 + l16) * 72 + kq];
          #pragma unroll
          for (int zt = 0; zt < 4; zt++) {
            frag8 kf = *(const frag8*)&shA[(zt * 16 + l16) * 264 + q * 64 + kq];
            sacc[zt] = MFMA_F16(wf, kf, sacc[zt]);
          }
        }
      }
      if (q < 3) __syncthreads();   // shWP reused by next quarter
    }
    // --- softmax rows m = w*16 + quad*4 + r over 64 z; P -> shWP (W quarter dead) ---
    if (w < 4) {
      #pragma unroll
      for (int r = 0; r < 4; r++) {
        float mx = fmaxf(fmaxf(sacc[0][r], sacc[1][r]), fmaxf(sacc[2][r], sacc[3][r]));
        #pragma unroll
        for (int off = 1; off < 16; off <<= 1) mx = fmaxf(mx, __shfl_xor(mx, off));
        float e0 = __expf(sacc[0][r] - mx), e1 = __expf(sacc[1][r] - mx);
        float e2 = __expf(sacc[2][r] - mx), e3 = __expf(sacc[3][r] - mx);
        float sum = e0 + e1 + e2 + e3;
        #pragma unroll
        for (int off = 1; off < 16; off <<= 1) sum += __shfl_xor(sum, off);
        float inv = 1.f / sum;
        int m = w * 16 + quad * 4 + r;
        shWP[m * 72 + l16 +  0] = (half_t)(e0 * inv);
        shWP[m * 72 + l16 + 16] = (half_t)(e1 * inv);
        shWP[m * 72 + l16 + 32] = (half_t)(e2 * inv);
        shWP[m * 72 + l16 + 48] = (half_t)(e3 * inv);
      }
    }
    __syncthreads();
    // --- PV: O[m][vout] = P @ VT^T; zacc += O * os[h]; wave w owns vout slice [w*32, +32) ---
    {
      frag8 pf[4][2];
      #pragma unroll
      for (int mf = 0; mf < 4; mf++)
        #pragma unroll
        for (int ks = 0; ks < 2; ks++)
          pf[mf][ks] = *(const frag8*)&shWP[(mf * 16 + l16) * 72 + ks * 32 + quad * 8];
      #pragma unroll
      for (int dt = 0; dt < 2; dt++) {
        frag8 vf0 = *(const frag8*)&shVT[(w * 32 + dt * 16 + l16) * 72 +  0 + quad * 8];
        frag8 vf1 = *(const frag8*)&shVT[(w * 32 + dt * 16 + l16) * 72 + 32 + quad * 8];
        #pragma unroll
        for (int mf = 0; mf < 4; mf++) {
          f32x4 oacc = (f32x4){0.f, 0.f, 0.f, 0.f};
          oacc = MFMA_F16(pf[mf][0], vf0, oacc);
          oacc = MFMA_F16(pf[mf][1], vf1, oacc);
          #pragma unroll
          for (int r = 0; r < 4; r++) zacc[mf][dt][r] += oacc[r] * osv[hh][dt];
        }
      }
    }
    __syncthreads();   // shWP/shVT reuse next head; also gates final shA overwrite
  }

  // --- Z writeback: stage f16 into shA (dead), then coalesced 16B stores (blocked layout) ---
  #pragma unroll
  for (int mf = 0; mf < 4; mf++)
    #pragma unroll
    for (int dt = 0; dt < 2; dt++)
      #pragma unroll
      for (int r = 0; r < 4; r++)
        shA[(mf * 16 + quad * 4 + r) * 264 + w * 32 + dt * 16 + l16] = (half_t)zacc[mf][dt][r];
  __syncthreads();
  #pragma unroll
  for (int i = 0; i < 4; i++) {
    int slot = i * 512 + tid;
    int grow = slot >> 5, c8 = (slot & 31) * 8;
    size_t zrow = mode ? ((size_t)(b * 64 + slice) * 64 + grow) : ((size_t)(b * 64 + grow) * 64 + slice);
    *(frag8*)&Z[zrow * 256 + c8] = *(const frag8*)&shA[grow * 264 + c8];
  }
}

// ---------------- residual + LN2; x2 -> d_out fp32, h -> f16 (Z = Z0 + Z1, BLOCKED layout) ----------------
__global__ __launch_bounds__(256) void ln2_kernel(
    const float* __restrict__ x, const half_t* __restrict__ Z0, const half_t* __restrict__ Z1,
    const float* __restrict__ w, const float* __restrict__ bia,
    float* __restrict__ x2out, half_t* __restrict__ hH) {
  int row  = blockIdx.x * 4 + (threadIdx.x >> 6);
  int lane = threadIdx.x & 63;
  size_t base = (size_t)row * 256 + lane * 4;
  int bb = row >> 12, p = row & 4095, hh = p >> 6, ww = p & 63;
  int m = (hh & 7) * 8 + (ww & 7), n = (hh >> 3) * 8 + (ww >> 3);
  size_t zbase = ((size_t)((bb * 64 + m) * 64 + n)) * 256 + lane * 4;
  float4 xv = *(const float4*)&x[base];
  half4_t zv0 = *(const half4_t*)&Z0[zbase];
  half4_t zv1 = *(const half4_t*)&Z1[zbase];
  float4 v;
  v.x = xv.x + (float)zv0[0] + (float)zv1[0];
  v.y = xv.y + (float)zv0[1] + (float)zv1[1];
  v.z = xv.z + (float)zv0[2] + (float)zv1[2];
  v.w = xv.w + (float)zv0[3] + (float)zv1[3];
  float s  = v.x + v.y + v.z + v.w;
  float sq = v.x * v.x + v.y * v.y + v.z * v.z + v.w * v.w;
  #pragma unroll
  for (int off = 1; off < 64; off <<= 1) { s += __shfl_xor(s, off); sq += __shfl_xor(sq, off); }
  float mean = s * (1.f / 256), var = sq * (1.f / 256) - mean * mean;
  float r = rsqrtf(var + EPSc);
  float4 wv = *(const float4*)&w[lane * 4];
  float4 bv = *(const float4*)&bia[lane * 4];
  *(float4*)&x2out[base] = v;
  half4_t y;
  y[0] = (half_t)((v.x - mean) * r * wv.x + bv.x);
  y[1] = (half_t)((v.y - mean) * r * wv.y + bv.y);
  y[2] = (half_t)((v.z - mean) * r * wv.z + bv.z);
  y[3] = (half_t)((v.w - mean) * r * wv.w + bv.w);
  *(half4_t*)&hH[base] = y;
}

extern "C" void kernel_launch(void* const* d_in, const int* in_sizes, int n_in,
                              void* d_out, int out_size, void* d_ws, size_t ws_size,
                              hipStream_t stream) {
  (void)in_sizes; (void)n_in; (void)out_size; (void)ws_size;
  const float* x    = (const float*)d_in[0];
  const float* ln1w = (const float*)d_in[1];
  const float* ln1b = (const float*)d_in[2];
  const float* q    = (const float*)d_in[3];
  const float* k    = (const float*)d_in[4];
  const float* v    = (const float*)d_in[5];
  const float* o    = (const float*)d_in[6];
  const float* ln2w = (const float*)d_in[7];
  const float* ln2b = (const float*)d_in[8];
  const float* w1   = (const float*)d_in[9];
  const float* b1   = (const float*)d_in[10];
  const float* w2   = (const float*)d_in[11];
  const float* b2   = (const float*)d_in[12];
  float* out = (float*)d_out;

  const size_t ROWS = (size_t)Bc * Tc;        // 32768
  const size_t ELTS = ROWS * Dc;              // 8,388,608
  const size_t MB16 = ELTS * sizeof(half_t);  // 16 MiB
  // ws plan (50 MiB used; 82 MiB verified safe in r7):
  //   [0:8K) os | [64K:1M+64K) Mt [h][e][d] | +1M: vt/w1t/w2t (128K each)
  //   [2M:18M)   aH f16 (blocked)  -> reused as hH after attention
  //   [18M:34M)  Z0 f16 (BLOCKED, heads 0-3)
  //   [34M:50M)  Z1 f16 (BLOCKED, heads 4-7) -> reused as tH after ln2
  char* ws = (char*)d_ws;
  float*  osumB = (float*)ws;
  half_t* Mt    = (half_t*)(ws + (64 << 10));
  half_t* vt    = (half_t*)(ws + (64 << 10) + (1 << 20));
  half_t* w1t   = (half_t*)(ws + (64 << 10) + (1 << 20) + (128 << 10));
  half_t* w2t   = (half_t*)(ws + (64 << 10) + (1 << 20) + (256 << 10));
  half_t* aH    = (half_t*)(ws + (2 << 20));
  half_t* Zb0   = (half_t*)(ws + (2 << 20) + MB16);
  half_t* Zb1   = (half_t*)(ws + (2 << 20) + 2 * MB16);
  half_t* hH    = aH;   // reuse (a dead after attention)
  half_t* tH    = Zb1;  // reuse (Z1 dead after ln2)

  osum_kernel <<<8,   256, 0, stream>>>(o, osumB);
  prepM_kernel<<<512, 256, 0, stream>>>(q, k, Mt);
  prepT_kernel<<<768, 256, 0, stream>>>(v, w1, w2, vt, w1t, w2t);
  ln1_kernel  <<<ROWS / 4, 256, 0, stream>>>(x, ln1w, ln1b, aH);
  // fused attention: ONE dispatch, 1024 blocks (512 mode-0 -> Z0, 512 mode-1 -> Z1)
  attn_kernel <<<1024, 512, 0, stream>>>(aH, Mt, vt, osumB, Zb0, Zb1);
  // residual + LN2 (sums Z0+Z1 in fp32)
  ln2_kernel  <<<ROWS / 4, 256, 0, stream>>>(x, Zb0, Zb1, ln2w, ln2b, out, hH);
  // MLP on the tiled GEMM: fc1 relu -> tH; fc2 +bias +resid -> out
  wgemm_kernel<<<512, 256, 0, stream>>>(hH, w1t, b1, nullptr, tH, 1, 256, 256);
  wgemm_kernel<<<512, 256, 0, stream>>>(tH, w2t, b2, out, nullptr, 2, 256, 256);
}

// Round 5
// 339.834 us; speedup vs baseline: 1.7093x; 1.5028x over previous
//
#include <hip/hip_runtime.h>

// (B, N, D, H) = (8, 4096, 256, 8), PS=8 -> image 64x64; blocked m=fine pos, n=tile idx.
// SPEC FACT 1: no softmax temperature; logit sigma ~16. f16 inputs + fp32 MFMA acc -> logit err ~0.01 (safe).
// SPEC FACT 2: Z = einsum('bhmnd,hdv->bmnd', O, o) is DIAGONAL in d, SUMS v:
//   Z[...,d] = sum_h O_h[...,d] * os[h][d], os[h][d] = sum_v o[h,d,v].
// SPEC FACT 3: S = (A M_h) A_g^T with M_h = q_h k^T. W = A·M_h computed IN-BLOCK, FULL 64x256 per head
//   (fat W-phase: 4 MFMA per global Mt load — r4's e-quartering dropped this to 1:1 and was
//   latency-bound at MfmaUtil 7.7%; DO NOT re-quarter the contraction).
// LDS PLAN: shA 33 KB + union(shVT 36 KB | shW 33 KB + shP 9 KB) = 75 KB -> 2 blocks/CU.
//   Enabler: each wave reads only 4 frag8 of VT (its rows w*32+dt*16+l16) -> register-cache them
//   once (vtreg), then shVT is dead and shW/shP overlay it.
// REGISTER LESSON (r3): __launch_bounds__(512,4) split the unified file 64/64 -> ~550 MB scratch
//   spill traffic. (512,2) compiles these shapes to 116-128 arch VGPR, zero spill. DO NOT TIGHTEN.
//   W-phase runs as two et-passes (wacc[4]=16 regs live) to stay <=128 with vtreg+zacc resident.
// MFMA conventions (verified r6/r7, absmax 0.125): mfma_f32_16x16x32_f16 computes C = A @ B^T:
//   A-frag: A[m = l16][k = quad*8 + j]; B-frag same over n-rows; C/D: col = l16, row = quad*4 + reg.
// Z kept in BLOCKED layout, TWO buffers (mode0 heads 0-3, mode1 heads 4-7); ln2 sums them in fp32.
#define Bc   8
#define Tc   4096
#define Dc   256
#define EPSc 1e-5f

typedef _Float16 half_t;
typedef __attribute__((ext_vector_type(4))) _Float16 half4_t;
typedef __attribute__((ext_vector_type(8))) _Float16 frag8;
typedef __attribute__((ext_vector_type(4))) float f32x4;

#define MFMA_F16(a, b, c) __builtin_amdgcn_mfma_f32_16x16x32_f16((a), (b), (c), 0, 0, 0)

// ---------------- os[h][d] = sum_v o[h,d,v] ----------------
__global__ __launch_bounds__(256) void osum_kernel(const float* __restrict__ o, float* __restrict__ os) {
  int h = blockIdx.x, d = threadIdx.x;
  const float* row = o + ((size_t)h * 256 + d) * 256;
  float s = 0.f;
  #pragma unroll 8
  for (int v = 0; v < 256; v += 4) {
    float4 r4 = *(const float4*)&row[v];
    s += r4.x + r4.y + r4.z + r4.w;
  }
  os[h * 256 + d] = s;
}

// ---------------- Mt[h][e][d] = M_h[d][e] = sum_i q[h][d][i]*k[e][i]  (f16) ----------------
// Tiled fp32 GEMM: 512 blocks = h(8) x etile(8) x dtile(8); 32x32 output tile per block.
__global__ __launch_bounds__(256) void prepM_kernel(const float* __restrict__ q,
                                                    const float* __restrict__ k,
                                                    half_t* __restrict__ Mt) {
  __shared__ float shK[32 * 260];   // 32.5 KB
  __shared__ float shQ[32 * 260];   // 32.5 KB  (65 KB total -> 2 blocks/CU)
  int tid = threadIdx.x;
  int h = blockIdx.x >> 6, et = (blockIdx.x >> 3) & 7, dt = blockIdx.x & 7;
  const float* kbase = k + (size_t)(et * 32) * 256;
  const float* qbase = q + ((size_t)h * 256 + dt * 32) * 256;
  #pragma unroll
  for (int r = 0; r < 8; r++) {
    int f = r * 256 + tid;                  // float4 slot 0..2047; one row per wave
    int row = f >> 6, c4 = (f & 63) * 4;
    *(float4*)&shK[row * 260 + c4] = *(const float4*)&kbase[(size_t)row * 256 + c4];
    *(float4*)&shQ[row * 260 + c4] = *(const float4*)&qbase[(size_t)row * 256 + c4];
  }
  __syncthreads();
  int e = tid & 31, dg = tid >> 5;          // thread -> (e, 4 consecutive d)
  const float* kr = &shK[e * 260];
  const float* q0 = &shQ[(dg * 4 + 0) * 260];
  const float* q1 = &shQ[(dg * 4 + 1) * 260];
  const float* q2 = &shQ[(dg * 4 + 2) * 260];
  const float* q3 = &shQ[(dg * 4 + 3) * 260];
  float a0 = 0.f, a1 = 0.f, a2 = 0.f, a3 = 0.f;
  #pragma unroll 4
  for (int kk = 0; kk < 256; kk += 4) {
    float4 kv = *(const float4*)&kr[kk];
    float4 v0 = *(const float4*)&q0[kk];
    float4 v1 = *(const float4*)&q1[kk];
    float4 v2 = *(const float4*)&q2[kk];
    float4 v3 = *(const float4*)&q3[kk];
    a0 += v0.x * kv.x + v0.y * kv.y + v0.z * kv.z + v0.w * kv.w;
    a1 += v1.x * kv.x + v1.y * kv.y + v1.z * kv.z + v1.w * kv.w;
    a2 += v2.x * kv.x + v2.y * kv.y + v2.z * kv.z + v2.w * kv.w;
    a3 += v3.x * kv.x + v3.y * kv.y + v3.z * kv.z + v3.w * kv.w;
  }
  half4_t outv;
  outv[0] = (half_t)a0; outv[1] = (half_t)a1; outv[2] = (half_t)a2; outv[3] = (half_t)a3;
  *(half4_t*)&Mt[((size_t)h * 256 + et * 32 + e) * 256 + dt * 32 + dg * 4] = outv;
}

// ---------------- transpose v/w1/w2 -> f16 [n][d] ----------------
__global__ __launch_bounds__(256) void prepT_kernel(const float* __restrict__ v,
                                                    const float* __restrict__ w1,
                                                    const float* __restrict__ w2,
                                                    half_t* vt, half_t* w1t, half_t* w2t) {
  int which = blockIdx.x >> 8, n = blockIdx.x & 255, d = threadIdx.x;
  const float* src = which == 0 ? v : (which == 1 ? w1 : w2);
  half_t* dst = which == 0 ? vt : (which == 1 ? w1t : w2t);
  dst[(size_t)n * 256 + d] = (half_t)src[(size_t)d * 256 + n];
}

// ---------------- LN1 + blocked permute -> f16; one wave per row ----------------
__global__ __launch_bounds__(256) void ln1_kernel(
    const float* __restrict__ x, const float* __restrict__ w,
    const float* __restrict__ bia, half_t* __restrict__ aH) {
  int row  = blockIdx.x * 4 + (threadIdx.x >> 6);
  int lane = threadIdx.x & 63;
  float4 v = *(const float4*)&x[(size_t)row * 256 + lane * 4];
  float s  = v.x + v.y + v.z + v.w;
  float sq = v.x * v.x + v.y * v.y + v.z * v.z + v.w * v.w;
  #pragma unroll
  for (int off = 1; off < 64; off <<= 1) { s += __shfl_xor(s, off); sq += __shfl_xor(sq, off); }
  float mean = s * (1.f / 256), var = sq * (1.f / 256) - mean * mean;
  float r = rsqrtf(var + EPSc);
  float4 wv = *(const float4*)&w[lane * 4];
  float4 bv = *(const float4*)&bia[lane * 4];
  half4_t y;
  y[0] = (half_t)((v.x - mean) * r * wv.x + bv.x);
  y[1] = (half_t)((v.y - mean) * r * wv.y + bv.y);
  y[2] = (half_t)((v.z - mean) * r * wv.z + bv.z);
  y[3] = (half_t)((v.w - mean) * r * wv.w + bv.w);
  int bb = row >> 12, p = row & 4095, hh = p >> 6, ww = p & 63;
  int m = (hh & 7) * 8 + (ww & 7), n = (hh >> 3) * 8 + (ww >> 3);
  *(half4_t*)&aH[((size_t)((bb * 64 + m) * 64 + n)) * 256 + lane * 4] = y;
}

// ---------------- tiled GEMM: C(128x128 tile) = A(Mx256) @ Bt(Nx256)^T, K=256 ----------------
// epi 1: +bias relu -> f16. epi 2: +bias, outf += (resid).   (epi 0 path retained)
__global__ __launch_bounds__(256) void wgemm_kernel(
    const half_t* __restrict__ A, const half_t* __restrict__ Bt,
    const float* __restrict__ bias, float* __restrict__ outf,
    half_t* __restrict__ outh, int epi, int ldn, int mtiles) {
  __shared__ half_t shA[128 * 72];   // 18 KB, stride 72: 16B-aligned rows, conflict-free
  __shared__ half_t shB[128 * 72];
  int tid = threadIdx.x, lane = tid & 63, wave = tid >> 6;
  int l16 = lane & 15, quad = lane >> 4;
  int mtile = blockIdx.x % mtiles, ntile = blockIdx.x / mtiles;
  int r0 = mtile * 128, n0 = ntile * 128;
  int wm = (wave >> 1) * 64, wn = (wave & 1) * 64;
  f32x4 acc[4][4];
  #pragma unroll
  for (int mt = 0; mt < 4; mt++)
    #pragma unroll
    for (int nt = 0; nt < 4; nt++) acc[mt][nt] = (f32x4){0.f, 0.f, 0.f, 0.f};
  for (int kb = 0; kb < 256; kb += 64) {
    if (kb) __syncthreads();
    #pragma unroll
    for (int rr = 0; rr < 4; rr++) {
      int idx = rr * 256 + tid;
      int row = idx >> 3, c8 = (idx & 7) * 8;
      *(frag8*)&shA[row * 72 + c8] = *(const frag8*)&A[(size_t)(r0 + row) * 256 + kb + c8];
      *(frag8*)&shB[row * 72 + c8] = *(const frag8*)&Bt[(size_t)(n0 + row) * 256 + kb + c8];
    }
    __syncthreads();
    #pragma unroll
    for (int kh = 0; kh < 2; kh++) {
      int ko = kh * 32 + quad * 8;
      frag8 af[4], bf[4];
      #pragma unroll
      for (int mt = 0; mt < 4; mt++) af[mt] = *(const frag8*)&shA[(wm + mt * 16 + l16) * 72 + ko];
      #pragma unroll
      for (int nt = 0; nt < 4; nt++) bf[nt] = *(const frag8*)&shB[(wn + nt * 16 + l16) * 72 + ko];
      #pragma unroll
      for (int mt = 0; mt < 4; mt++)
        #pragma unroll
        for (int nt = 0; nt < 4; nt++) acc[mt][nt] = MFMA_F16(af[mt], bf[nt], acc[mt][nt]);
    }
  }
  #pragma unroll
  for (int mt = 0; mt < 4; mt++)
    #pragma unroll
    for (int nt = 0; nt < 4; nt++)
      #pragma unroll
      for (int r = 0; r < 4; r++) {
        int row = r0 + wm + mt * 16 + quad * 4 + r;
        int col = n0 + wn + nt * 16 + l16;
        float vv = acc[mt][nt][r];
        if (epi) vv += bias[col];
        if (epi == 1) vv = fmaxf(vv, 0.f);
        size_t idx = (size_t)row * ldn + col;
        if (epi == 2) outf[idx] = vv + outf[idx];
        else          outh[idx] = (half_t)vv;
      }
}

// ---------------- fully fused attention: W + score + softmax + PV, 4 heads per block ----------------
// One 512-thread block per (mode, b, slice). 8 waves. LDS 75 KB -> 2 blocks/CU.
// Grid 1024: g<512 -> mode 0 (group (b, n=slice), heads 0-3, Z0); g>=512 -> mode 1 (heads 4-7, Z1).
// Fat W-phase (full 64x256 per head, 4 MFMA per Mt load); 2 barriers per head.
// VT register-cached per wave (vtreg) -> shVT LDS overlaid by shW/shP after the cache load.
__global__ __launch_bounds__(512, 2) void attn_kernel(
    const half_t* __restrict__ aH, const half_t* __restrict__ Mt,
    const half_t* __restrict__ vt, const float* __restrict__ osum,
    half_t* __restrict__ Z0, half_t* __restrict__ Z1) {
  __shared__ half_t shA[64 * 264];               // A_g[z][d], 33.0 KB
  __shared__ half_t shU[64 * 264 + 64 * 72];     // union: shVT(256x72=36KB) | shW(64x264=33KB)+shP(64x72=9KB)
  half_t* shVT = shU;
  half_t* shW  = shU;
  half_t* shP  = shU + 64 * 264;
  int tid = threadIdx.x, lane = tid & 63, w = tid >> 6;
  int l16 = lane & 15, quad = lane >> 4;
  int g = blockIdx.x;
  int mode = g >> 9, gg = g & 511, b = gg >> 6, slice = gg & 63;
  int hbase = mode * 4;
  half_t* Z = mode ? Z1 : Z0;

  // --- stage A_g (64x256 f16 = 32 KB), coalesced ---
  #pragma unroll
  for (int i = 0; i < 4; i++) {
    int slot = i * 512 + tid;
    int z = slot >> 5, c8 = (slot & 31) * 8;
    size_t rz = mode ? ((size_t)(b * 64 + slice) * 64 + z) : ((size_t)(b * 64 + z) * 64 + slice);
    *(frag8*)&shA[z * 264 + c8] = *(const frag8*)&aH[rz * 256 + c8];
  }
  __syncthreads();

  // --- vtrans: VT_g[vout][z] = sum_d v[d][vout] A_g[z][d]; wave w owns vout in [w*32, w*32+32) ---
  {
    f32x4 vacc[2][4];
    #pragma unroll
    for (int dt = 0; dt < 2; dt++)
      #pragma unroll
      for (int zt = 0; zt < 4; zt++) vacc[dt][zt] = (f32x4){0.f, 0.f, 0.f, 0.f};
    for (int ks = 0; ks < 8; ks++) {
      int k0 = ks * 32 + quad * 8;
      frag8 afr[2], bfr[4];
      #pragma unroll
      for (int dt = 0; dt < 2; dt++)
        afr[dt] = *(const frag8*)&vt[(size_t)(w * 32 + dt * 16 + l16) * 256 + k0];
      #pragma unroll
      for (int zt = 0; zt < 4; zt++)
        bfr[zt] = *(const frag8*)&shA[(zt * 16 + l16) * 264 + k0];
      #pragma unroll
      for (int dt = 0; dt < 2; dt++)
        #pragma unroll
        for (int zt = 0; zt < 4; zt++) vacc[dt][zt] = MFMA_F16(afr[dt], bfr[zt], vacc[dt][zt]);
    }
    #pragma unroll
    for (int dt = 0; dt < 2; dt++)
      #pragma unroll
      for (int zt = 0; zt < 4; zt++)
        #pragma unroll
        for (int r = 0; r < 4; r++)
          shVT[(w * 32 + dt * 16 + quad * 4 + r) * 72 + zt * 16 + l16] = (half_t)vacc[dt][zt][r];
  }
  __syncthreads();

  // --- register-cache this wave's VT fragments (rows w*32+dt*16+l16, both k-halves) ---
  frag8 vtreg[2][2];
  #pragma unroll
  for (int dt = 0; dt < 2; dt++)
    #pragma unroll
    for (int ks = 0; ks < 2; ks++)
      vtreg[dt][ks] = *(const frag8*)&shVT[(w * 32 + dt * 16 + l16) * 72 + ks * 32 + quad * 8];

  // preload os[h][d] for this wave's d-slice
  float osv[4][2];
  #pragma unroll
  for (int hh = 0; hh < 4; hh++)
    #pragma unroll
    for (int dt = 0; dt < 2; dt++)
      osv[hh][dt] = osum[(hbase + hh) * 256 + w * 32 + dt * 16 + l16];

  f32x4 zacc[4][2];   // fp32 Z accumulator: [m-frag][d-sub], d = w*32 + dt*16 + l16
  #pragma unroll
  for (int mf = 0; mf < 4; mf++)
    #pragma unroll
    for (int dt = 0; dt < 2; dt++) zacc[mf][dt] = (f32x4){0.f, 0.f, 0.f, 0.f};
  __syncthreads();   // vtreg loaded by all waves; shU free for shW overlay

  for (int hh = 0; hh < 4; hh++) {
    const half_t* Mth = Mt + (size_t)(hbase + hh) * 65536;
    // --- W-phase: W[m][e] = sum_d A_g[m][d] Mt_h[e][d]; wave owns e in [w*32,+32), two et passes ---
    #pragma unroll
    for (int et = 0; et < 2; et++) {
      f32x4 wacc[4];
      #pragma unroll
      for (int mf = 0; mf < 4; mf++) wacc[mf] = (f32x4){0.f, 0.f, 0.f, 0.f};
      #pragma unroll
      for (int ks = 0; ks < 8; ks++) {
        int k0 = ks * 32 + quad * 8;
        frag8 bf = *(const frag8*)&Mth[(size_t)(w * 32 + et * 16 + l16) * 256 + k0];
        #pragma unroll
        for (int mf = 0; mf < 4; mf++) {
          frag8 af = *(const frag8*)&shA[(mf * 16 + l16) * 264 + k0];
          wacc[mf] = MFMA_F16(af, bf, wacc[mf]);
        }
      }
      #pragma unroll
      for (int mf = 0; mf < 4; mf++)
        #pragma unroll
        for (int r = 0; r < 4; r++)
          shW[(mf * 16 + quad * 4 + r) * 264 + w * 32 + et * 16 + l16] = (half_t)wacc[mf][r];
    }
    __syncthreads();
    // --- S = W @ A_g^T (contraction over e=256) + softmax; waves 0-3, m = w*16 + l16 ---
    if (w < 4) {
      f32x4 sacc[4];
      #pragma unroll
      for (int zt = 0; zt < 4; zt++) sacc[zt] = (f32x4){0.f, 0.f, 0.f, 0.f};
      #pragma unroll
      for (int ks = 0; ks < 8; ks++) {
        int k0 = ks * 32 + quad * 8;
        frag8 wf = *(const frag8*)&shW[(w * 16 + l16) * 264 + k0];
        #pragma unroll
        for (int zt = 0; zt < 4; zt++) {
          frag8 kf = *(const frag8*)&shA[(zt * 16 + l16) * 264 + k0];
          sacc[zt] = MFMA_F16(wf, kf, sacc[zt]);
        }
      }
      #pragma unroll
      for (int r = 0; r < 4; r++) {
        float mx = fmaxf(fmaxf(sacc[0][r], sacc[1][r]), fmaxf(sacc[2][r], sacc[3][r]));
        #pragma unroll
        for (int off = 1; off < 16; off <<= 1) mx = fmaxf(mx, __shfl_xor(mx, off));
        float e0 = __expf(sacc[0][r] - mx), e1 = __expf(sacc[1][r] - mx);
        float e2 = __expf(sacc[2][r] - mx), e3 = __expf(sacc[3][r] - mx);
        float sum = e0 + e1 + e2 + e3;
        #pragma unroll
        for (int off = 1; off < 16; off <<= 1) sum += __shfl_xor(sum, off);
        float inv = 1.f / sum;
        int m = w * 16 + quad * 4 + r;
        shP[m * 72 + l16 +  0] = (half_t)(e0 * inv);
        shP[m * 72 + l16 + 16] = (half_t)(e1 * inv);
        shP[m * 72 + l16 + 32] = (half_t)(e2 * inv);
        shP[m * 72 + l16 + 48] = (half_t)(e3 * inv);
      }
    }
    __syncthreads();
    // --- PV: O[m][vout] = P @ VT^T (VT in registers); zacc += O * os[h] ---
    // No barrier after PV: next W-phase writes only shW (disjoint from shP), and the
    // post-W barrier orders all PV shP reads before the next S-phase shP writes.
    #pragma unroll
    for (int mf = 0; mf < 4; mf++) {
      frag8 pf0 = *(const frag8*)&shP[(mf * 16 + l16) * 72 +  0 + quad * 8];
      frag8 pf1 = *(const frag8*)&shP[(mf * 16 + l16) * 72 + 32 + quad * 8];
      #pragma unroll
      for (int dt = 0; dt < 2; dt++) {
        f32x4 oacc = (f32x4){0.f, 0.f, 0.f, 0.f};
        oacc = MFMA_F16(pf0, vtreg[dt][0], oacc);
        oacc = MFMA_F16(pf1, vtreg[dt][1], oacc);
        #pragma unroll
        for (int r = 0; r < 4; r++) zacc[mf][dt][r] += oacc[r] * osv[hh][dt];
      }
    }
  }

  // --- Z writeback: stage f16 into shA (dead after last S-phase), coalesced 16B stores ---
  #pragma unroll
  for (int mf = 0; mf < 4; mf++)
    #pragma unroll
    for (int dt = 0; dt < 2; dt++)
      #pragma unroll
      for (int r = 0; r < 4; r++)
        shA[(mf * 16 + quad * 4 + r) * 264 + w * 32 + dt * 16 + l16] = (half_t)zacc[mf][dt][r];
  __syncthreads();
  #pragma unroll
  for (int i = 0; i < 4; i++) {
    int slot = i * 512 + tid;
    int grow = slot >> 5, c8 = (slot & 31) * 8;
    size_t zrow = mode ? ((size_t)(b * 64 + slice) * 64 + grow) : ((size_t)(b * 64 + grow) * 64 + slice);
    *(frag8*)&Z[zrow * 256 + c8] = *(const frag8*)&shA[grow * 264 + c8];
  }
}

// ---------------- residual + LN2; x2 -> d_out fp32, h -> f16 (Z = Z0 + Z1, BLOCKED layout) ----------------
__global__ __launch_bounds__(256) void ln2_kernel(
    const float* __restrict__ x, const half_t* __restrict__ Z0, const half_t* __restrict__ Z1,
    const float* __restrict__ w, const float* __restrict__ bia,
    float* __restrict__ x2out, half_t* __restrict__ hH) {
  int row  = blockIdx.x * 4 + (threadIdx.x >> 6);
  int lane = threadIdx.x & 63;
  size_t base = (size_t)row * 256 + lane * 4;
  int bb = row >> 12, p = row & 4095, hh = p >> 6, ww = p & 63;
  int m = (hh & 7) * 8 + (ww & 7), n = (hh >> 3) * 8 + (ww >> 3);
  size_t zbase = ((size_t)((bb * 64 + m) * 64 + n)) * 256 + lane * 4;
  float4 xv = *(const float4*)&x[base];
  half4_t zv0 = *(const half4_t*)&Z0[zbase];
  half4_t zv1 = *(const half4_t*)&Z1[zbase];
  float4 v;
  v.x = xv.x + (float)zv0[0] + (float)zv1[0];
  v.y = xv.y + (float)zv0[1] + (float)zv1[1];
  v.z = xv.z + (float)zv0[2] + (float)zv1[2];
  v.w = xv.w + (float)zv0[3] + (float)zv1[3];
  float s  = v.x + v.y + v.z + v.w;
  float sq = v.x * v.x + v.y * v.y + v.z * v.z + v.w * v.w;
  #pragma unroll
  for (int off = 1; off < 64; off <<= 1) { s += __shfl_xor(s, off); sq += __shfl_xor(sq, off); }
  float mean = s * (1.f / 256), var = sq * (1.f / 256) - mean * mean;
  float r = rsqrtf(var + EPSc);
  float4 wv = *(const float4*)&w[lane * 4];
  float4 bv = *(const float4*)&bia[lane * 4];
  *(float4*)&x2out[base] = v;
  half4_t y;
  y[0] = (half_t)((v.x - mean) * r * wv.x + bv.x);
  y[1] = (half_t)((v.y - mean) * r * wv.y + bv.y);
  y[2] = (half_t)((v.z - mean) * r * wv.z + bv.z);
  y[3] = (half_t)((v.w - mean) * r * wv.w + bv.w);
  *(half4_t*)&hH[base] = y;
}

extern "C" void kernel_launch(void* const* d_in, const int* in_sizes, int n_in,
                              void* d_out, int out_size, void* d_ws, size_t ws_size,
                              hipStream_t stream) {
  (void)in_sizes; (void)n_in; (void)out_size; (void)ws_size;
  const float* x    = (const float*)d_in[0];
  const float* ln1w = (const float*)d_in[1];
  const float* ln1b = (const float*)d_in[2];
  const float* q    = (const float*)d_in[3];
  const float* k    = (const float*)d_in[4];
  const float* v    = (const float*)d_in[5];
  const float* o    = (const float*)d_in[6];
  const float* ln2w = (const float*)d_in[7];
  const float* ln2b = (const float*)d_in[8];
  const float* w1   = (const float*)d_in[9];
  const float* b1   = (const float*)d_in[10];
  const float* w2   = (const float*)d_in[11];
  const float* b2   = (const float*)d_in[12];
  float* out = (float*)d_out;

  const size_t ROWS = (size_t)Bc * Tc;        // 32768
  const size_t ELTS = ROWS * Dc;              // 8,388,608
  const size_t MB16 = ELTS * sizeof(half_t);  // 16 MiB
  // ws plan (50 MiB used; 82 MiB verified safe in r7):
  //   [0:8K) os | [64K:1M+64K) Mt [h][e][d] | +1M: vt/w1t/w2t (128K each)
  //   [2M:18M)   aH f16 (blocked)  -> reused as hH after attention
  //   [18M:34M)  Z0 f16 (BLOCKED, heads 0-3)
  //   [34M:50M)  Z1 f16 (BLOCKED, heads 4-7) -> reused as tH after ln2
  char* ws = (char*)d_ws;
  float*  osumB = (float*)ws;
  half_t* Mt    = (half_t*)(ws + (64 << 10));
  half_t* vt    = (half_t*)(ws + (64 << 10) + (1 << 20));
  half_t* w1t   = (half_t*)(ws + (64 << 10) + (1 << 20) + (128 << 10));
  half_t* w2t   = (half_t*)(ws + (64 << 10) + (1 << 20) + (256 << 10));
  half_t* aH    = (half_t*)(ws + (2 << 20));
  half_t* Zb0   = (half_t*)(ws + (2 << 20) + MB16);
  half_t* Zb1   = (half_t*)(ws + (2 << 20) + 2 * MB16);
  half_t* hH    = aH;   // reuse (a dead after attention)
  half_t* tH    = Zb1;  // reuse (Z1 dead after ln2)

  osum_kernel <<<8,   256, 0, stream>>>(o, osumB);
  prepM_kernel<<<512, 256, 0, stream>>>(q, k, Mt);
  prepT_kernel<<<768, 256, 0, stream>>>(v, w1, w2, vt, w1t, w2t);
  ln1_kernel  <<<ROWS / 4, 256, 0, stream>>>(x, ln1w, ln1b, aH);
  // fused attention: ONE dispatch, 1024 blocks (512 mode-0 -> Z0, 512 mode-1 -> Z1), 2 blocks/CU
  attn_kernel <<<1024, 512, 0, stream>>>(aH, Mt, vt, osumB, Zb0, Zb1);
  // residual + LN2 (sums Z0+Z1 in fp32)
  ln2_kernel  <<<ROWS / 4, 256, 0, stream>>>(x, Zb0, Zb1, ln2w, ln2b, out, hH);
  // MLP on the tiled GEMM: fc1 relu -> tH; fc2 +bias +resid -> out
  wgemm_kernel<<<512, 256, 0, stream>>>(hH, w1t, b1, nullptr, tH, 1, 256, 256);
  wgemm_kernel<<<512, 256, 0, stream>>>(tH, w2t, b2, out, nullptr, 2, 256, 256);
}

// Round 6
// 315.469 us; speedup vs baseline: 1.8413x; 1.0772x over previous
//
#include <hip/hip_runtime.h>

// (B, N, D, H) = (8, 4096, 256, 8), PS=8 -> image 64x64; blocked m=fine pos, n=tile idx.
// SPEC FACT 1: no softmax temperature; logit sigma ~16. f16 inputs + fp32 MFMA acc -> logit err ~0.01 (safe).
// SPEC FACT 2: Z = einsum('bhmnd,hdv->bmnd', O, o) is DIAGONAL in d, SUMS v:
//   Z[...,d] = sum_h O_h[...,d] * os[h][d], os[h][d] = sum_v o[h,d,v].
// SPEC FACT 3: S = (A M_h) A_g^T with M_h = q_h k^T. W = A·M_h computed IN-BLOCK, FULL 64x256 per head.
// ILP LESSON (r5): with (512,2) the compiler chose VGPR=72 -> W-phase ran load->wait(250cy)->4 MFMA
//   serialized (MfmaUtil 17%, block time 37 us, identical to r2). Blocks run 1/CU regardless of the
//   75 KB LDS diet, so the register budget is FREE up to 256/wave: batch-prefetch the next head's Mt
//   into regs (bfp[2][8]) during the current head's S-phase, batch vt (vpre) and wf (wf_all) loads,
//   hoist shA af reads out of the et loop. sched_barrier(0) pins the prefetch issuance.
// REGISTER LESSON (r3): __launch_bounds__(512,4) clamped to 64 VGPR -> 550 MB spill. Keep (512,2).
// MFMA conventions (verified r6/r7, absmax 0.125): mfma_f32_16x16x32_f16 computes C = A @ B^T:
//   A-frag: A[m = l16][k = quad*8 + j]; B-frag same over n-rows; C/D: col = l16, row = quad*4 + reg.
// Z kept in BLOCKED layout, TWO buffers (mode0 heads 0-3, mode1 heads 4-7); ln2 sums them in fp32.
#define Bc   8
#define Tc   4096
#define Dc   256
#define EPSc 1e-5f

typedef _Float16 half_t;
typedef __attribute__((ext_vector_type(4))) _Float16 half4_t;
typedef __attribute__((ext_vector_type(8))) _Float16 frag8;
typedef __attribute__((ext_vector_type(4))) float f32x4;

#define MFMA_F16(a, b, c) __builtin_amdgcn_mfma_f32_16x16x32_f16((a), (b), (c), 0, 0, 0)

// ---------------- os[h][d] = sum_v o[h,d,v] ----------------
__global__ __launch_bounds__(256) void osum_kernel(const float* __restrict__ o, float* __restrict__ os) {
  int h = blockIdx.x, d = threadIdx.x;
  const float* row = o + ((size_t)h * 256 + d) * 256;
  float s = 0.f;
  #pragma unroll 8
  for (int v = 0; v < 256; v += 4) {
    float4 r4 = *(const float4*)&row[v];
    s += r4.x + r4.y + r4.z + r4.w;
  }
  os[h * 256 + d] = s;
}

// ---------------- Mt[h][e][d] = M_h[d][e] = sum_i q[h][d][i]*k[e][i]  (f16) ----------------
__global__ __launch_bounds__(256) void prepM_kernel(const float* __restrict__ q,
                                                    const float* __restrict__ k,
                                                    half_t* __restrict__ Mt) {
  __shared__ float shK[32 * 260];   // 32.5 KB
  __shared__ float shQ[32 * 260];   // 32.5 KB  (65 KB total)
  int tid = threadIdx.x;
  int h = blockIdx.x >> 6, et = (blockIdx.x >> 3) & 7, dt = blockIdx.x & 7;
  const float* kbase = k + (size_t)(et * 32) * 256;
  const float* qbase = q + ((size_t)h * 256 + dt * 32) * 256;
  #pragma unroll
  for (int r = 0; r < 8; r++) {
    int f = r * 256 + tid;
    int row = f >> 6, c4 = (f & 63) * 4;
    *(float4*)&shK[row * 260 + c4] = *(const float4*)&kbase[(size_t)row * 256 + c4];
    *(float4*)&shQ[row * 260 + c4] = *(const float4*)&qbase[(size_t)row * 256 + c4];
  }
  __syncthreads();
  int e = tid & 31, dg = tid >> 5;
  const float* kr = &shK[e * 260];
  const float* q0 = &shQ[(dg * 4 + 0) * 260];
  const float* q1 = &shQ[(dg * 4 + 1) * 260];
  const float* q2 = &shQ[(dg * 4 + 2) * 260];
  const float* q3 = &shQ[(dg * 4 + 3) * 260];
  float a0 = 0.f, a1 = 0.f, a2 = 0.f, a3 = 0.f;
  #pragma unroll 4
  for (int kk = 0; kk < 256; kk += 4) {
    float4 kv = *(const float4*)&kr[kk];
    float4 v0 = *(const float4*)&q0[kk];
    float4 v1 = *(const float4*)&q1[kk];
    float4 v2 = *(const float4*)&q2[kk];
    float4 v3 = *(const float4*)&q3[kk];
    a0 += v0.x * kv.x + v0.y * kv.y + v0.z * kv.z + v0.w * kv.w;
    a1 += v1.x * kv.x + v1.y * kv.y + v1.z * kv.z + v1.w * kv.w;
    a2 += v2.x * kv.x + v2.y * kv.y + v2.z * kv.z + v2.w * kv.w;
    a3 += v3.x * kv.x + v3.y * kv.y + v3.z * kv.z + v3.w * kv.w;
  }
  half4_t outv;
  outv[0] = (half_t)a0; outv[1] = (half_t)a1; outv[2] = (half_t)a2; outv[3] = (half_t)a3;
  *(half4_t*)&Mt[((size_t)h * 256 + et * 32 + e) * 256 + dt * 32 + dg * 4] = outv;
}

// ---------------- transpose v/w1/w2 -> f16 [n][d] ----------------
__global__ __launch_bounds__(256) void prepT_kernel(const float* __restrict__ v,
                                                    const float* __restrict__ w1,
                                                    const float* __restrict__ w2,
                                                    half_t* vt, half_t* w1t, half_t* w2t) {
  int which = blockIdx.x >> 8, n = blockIdx.x & 255, d = threadIdx.x;
  const float* src = which == 0 ? v : (which == 1 ? w1 : w2);
  half_t* dst = which == 0 ? vt : (which == 1 ? w1t : w2t);
  dst[(size_t)n * 256 + d] = (half_t)src[(size_t)d * 256 + n];
}

// ---------------- LN1 + blocked permute -> f16; one wave per row ----------------
__global__ __launch_bounds__(256) void ln1_kernel(
    const float* __restrict__ x, const float* __restrict__ w,
    const float* __restrict__ bia, half_t* __restrict__ aH) {
  int row  = blockIdx.x * 4 + (threadIdx.x >> 6);
  int lane = threadIdx.x & 63;
  float4 v = *(const float4*)&x[(size_t)row * 256 + lane * 4];
  float s  = v.x + v.y + v.z + v.w;
  float sq = v.x * v.x + v.y * v.y + v.z * v.z + v.w * v.w;
  #pragma unroll
  for (int off = 1; off < 64; off <<= 1) { s += __shfl_xor(s, off); sq += __shfl_xor(sq, off); }
  float mean = s * (1.f / 256), var = sq * (1.f / 256) - mean * mean;
  float r = rsqrtf(var + EPSc);
  float4 wv = *(const float4*)&w[lane * 4];
  float4 bv = *(const float4*)&bia[lane * 4];
  half4_t y;
  y[0] = (half_t)((v.x - mean) * r * wv.x + bv.x);
  y[1] = (half_t)((v.y - mean) * r * wv.y + bv.y);
  y[2] = (half_t)((v.z - mean) * r * wv.z + bv.z);
  y[3] = (half_t)((v.w - mean) * r * wv.w + bv.w);
  int bb = row >> 12, p = row & 4095, hh = p >> 6, ww = p & 63;
  int m = (hh & 7) * 8 + (ww & 7), n = (hh >> 3) * 8 + (ww >> 3);
  *(half4_t*)&aH[((size_t)((bb * 64 + m) * 64 + n)) * 256 + lane * 4] = y;
}

// ---------------- tiled GEMM: C(128x128 tile) = A(Mx256) @ Bt(Nx256)^T, K=256 ----------------
__global__ __launch_bounds__(256) void wgemm_kernel(
    const half_t* __restrict__ A, const half_t* __restrict__ Bt,
    const float* __restrict__ bias, float* __restrict__ outf,
    half_t* __restrict__ outh, int epi, int ldn, int mtiles) {
  __shared__ half_t shA[128 * 72];
  __shared__ half_t shB[128 * 72];
  int tid = threadIdx.x, lane = tid & 63, wave = tid >> 6;
  int l16 = lane & 15, quad = lane >> 4;
  int mtile = blockIdx.x % mtiles, ntile = blockIdx.x / mtiles;
  int r0 = mtile * 128, n0 = ntile * 128;
  int wm = (wave >> 1) * 64, wn = (wave & 1) * 64;
  f32x4 acc[4][4];
  #pragma unroll
  for (int mt = 0; mt < 4; mt++)
    #pragma unroll
    for (int nt = 0; nt < 4; nt++) acc[mt][nt] = (f32x4){0.f, 0.f, 0.f, 0.f};
  for (int kb = 0; kb < 256; kb += 64) {
    if (kb) __syncthreads();
    #pragma unroll
    for (int rr = 0; rr < 4; rr++) {
      int idx = rr * 256 + tid;
      int row = idx >> 3, c8 = (idx & 7) * 8;
      *(frag8*)&shA[row * 72 + c8] = *(const frag8*)&A[(size_t)(r0 + row) * 256 + kb + c8];
      *(frag8*)&shB[row * 72 + c8] = *(const frag8*)&Bt[(size_t)(n0 + row) * 256 + kb + c8];
    }
    __syncthreads();
    #pragma unroll
    for (int kh = 0; kh < 2; kh++) {
      int ko = kh * 32 + quad * 8;
      frag8 af[4], bf[4];
      #pragma unroll
      for (int mt = 0; mt < 4; mt++) af[mt] = *(const frag8*)&shA[(wm + mt * 16 + l16) * 72 + ko];
      #pragma unroll
      for (int nt = 0; nt < 4; nt++) bf[nt] = *(const frag8*)&shB[(wn + nt * 16 + l16) * 72 + ko];
      #pragma unroll
      for (int mt = 0; mt < 4; mt++)
        #pragma unroll
        for (int nt = 0; nt < 4; nt++) acc[mt][nt] = MFMA_F16(af[mt], bf[nt], acc[mt][nt]);
    }
  }
  #pragma unroll
  for (int mt = 0; mt < 4; mt++)
    #pragma unroll
    for (int nt = 0; nt < 4; nt++)
      #pragma unroll
      for (int r = 0; r < 4; r++) {
        int row = r0 + wm + mt * 16 + quad * 4 + r;
        int col = n0 + wn + nt * 16 + l16;
        float vv = acc[mt][nt][r];
        if (epi) vv += bias[col];
        if (epi == 1) vv = fmaxf(vv, 0.f);
        size_t idx = (size_t)row * ldn + col;
        if (epi == 2) outf[idx] = vv + outf[idx];
        else          outh[idx] = (half_t)vv;
      }
}

// ---------------- fully fused attention: W + score + softmax + PV, 4 heads per block ----------------
// One 512-thread block per (mode, b, slice). 8 waves. LDS 75 KB.
// Deep-ILP schedule: Mt fragments for head hh+1 register-prefetched (bfp) during head hh's S-phase.
__global__ __launch_bounds__(512, 2) void attn_kernel(
    const half_t* __restrict__ aH, const half_t* __restrict__ Mt,
    const half_t* __restrict__ vt, const float* __restrict__ osum,
    half_t* __restrict__ Z0, half_t* __restrict__ Z1) {
  __shared__ half_t shA[64 * 264];               // A_g[z][d], 33.0 KB
  __shared__ half_t shU[64 * 264 + 64 * 72];     // union: shVT(256x72=36KB) | shW(33KB)+shP(9KB)
  half_t* shVT = shU;
  half_t* shW  = shU;
  half_t* shP  = shU + 64 * 264;
  int tid = threadIdx.x, lane = tid & 63, w = tid >> 6;
  int l16 = lane & 15, quad = lane >> 4;
  int g = blockIdx.x;
  int mode = g >> 9, gg = g & 511, b = gg >> 6, slice = gg & 63;
  int hbase = mode * 4;
  half_t* Z = mode ? Z1 : Z0;

  // --- stage A_g (64x256 f16 = 32 KB), coalesced ---
  #pragma unroll
  for (int i = 0; i < 4; i++) {
    int slot = i * 512 + tid;
    int z = slot >> 5, c8 = (slot & 31) * 8;
    size_t rz = mode ? ((size_t)(b * 64 + slice) * 64 + z) : ((size_t)(b * 64 + z) * 64 + slice);
    *(frag8*)&shA[z * 264 + c8] = *(const frag8*)&aH[rz * 256 + c8];
  }

  // --- batch-issue vt fragments (consumed by vtrans) then head-0 Mt fragments (consumed by W(0)) ---
  frag8 vpre[2][8];
  #pragma unroll
  for (int ks = 0; ks < 8; ks++)
    #pragma unroll
    for (int dt = 0; dt < 2; dt++)
      vpre[dt][ks] = *(const frag8*)&vt[(size_t)(w * 32 + dt * 16 + l16) * 256 + ks * 32 + quad * 8];
  frag8 bfp[2][8];   // next-W-phase Mt fragments, rows w*32+et*16+l16
  {
    const half_t* M0 = Mt + (size_t)hbase * 65536;
    #pragma unroll
    for (int et = 0; et < 2; et++)
      #pragma unroll
      for (int ks = 0; ks < 8; ks++)
        bfp[et][ks] = *(const frag8*)&M0[(size_t)(w * 32 + et * 16 + l16) * 256 + ks * 32 + quad * 8];
  }
  __builtin_amdgcn_sched_barrier(0);   // pin prefetch issuance before the barrier/compute below
  __syncthreads();

  // --- vtrans: VT_g[vout][z] = sum_d v[d][vout] A_g[z][d]; wave w owns vout in [w*32, w*32+32) ---
  {
    f32x4 vacc[2][4];
    #pragma unroll
    for (int dt = 0; dt < 2; dt++)
      #pragma unroll
      for (int zt = 0; zt < 4; zt++) vacc[dt][zt] = (f32x4){0.f, 0.f, 0.f, 0.f};
    #pragma unroll
    for (int ks = 0; ks < 8; ks++) {
      int k0 = ks * 32 + quad * 8;
      frag8 bfr[4];
      #pragma unroll
      for (int zt = 0; zt < 4; zt++)
        bfr[zt] = *(const frag8*)&shA[(zt * 16 + l16) * 264 + k0];
      #pragma unroll
      for (int dt = 0; dt < 2; dt++)
        #pragma unroll
        for (int zt = 0; zt < 4; zt++) vacc[dt][zt] = MFMA_F16(vpre[dt][ks], bfr[zt], vacc[dt][zt]);
    }
    #pragma unroll
    for (int dt = 0; dt < 2; dt++)
      #pragma unroll
      for (int zt = 0; zt < 4; zt++)
        #pragma unroll
        for (int r = 0; r < 4; r++)
          shVT[(w * 32 + dt * 16 + quad * 4 + r) * 72 + zt * 16 + l16] = (half_t)vacc[dt][zt][r];
  }
  __syncthreads();

  // --- register-cache this wave's VT fragments (rows w*32+dt*16+l16, both k-halves) ---
  frag8 vtreg[2][2];
  #pragma unroll
  for (int dt = 0; dt < 2; dt++)
    #pragma unroll
    for (int ks = 0; ks < 2; ks++)
      vtreg[dt][ks] = *(const frag8*)&shVT[(w * 32 + dt * 16 + l16) * 72 + ks * 32 + quad * 8];

  float osv[4][2];
  #pragma unroll
  for (int hh = 0; hh < 4; hh++)
    #pragma unroll
    for (int dt = 0; dt < 2; dt++)
      osv[hh][dt] = osum[(hbase + hh) * 256 + w * 32 + dt * 16 + l16];

  f32x4 zacc[4][2];   // fp32 Z accumulator: [m-frag][d-sub], d = w*32 + dt*16 + l16
  #pragma unroll
  for (int mf = 0; mf < 4; mf++)
    #pragma unroll
    for (int dt = 0; dt < 2; dt++) zacc[mf][dt] = (f32x4){0.f, 0.f, 0.f, 0.f};
  __syncthreads();   // vtreg loaded; shU free for shW overlay

  #pragma unroll
  for (int hh = 0; hh < 4; hh++) {
    // --- W-phase (all regs): W[m][e] = sum_d A_g[m][d] Mt_h[e][d]; af hoisted across et ---
    {
      f32x4 wacc[2][4];
      #pragma unroll
      for (int et = 0; et < 2; et++)
        #pragma unroll
        for (int mf = 0; mf < 4; mf++) wacc[et][mf] = (f32x4){0.f, 0.f, 0.f, 0.f};
      #pragma unroll
      for (int ks = 0; ks < 8; ks++) {
        int k0 = ks * 32 + quad * 8;
        frag8 af[4];
        #pragma unroll
        for (int mf = 0; mf < 4; mf++) af[mf] = *(const frag8*)&shA[(mf * 16 + l16) * 264 + k0];
        #pragma unroll
        for (int et = 0; et < 2; et++)
          #pragma unroll
          for (int mf = 0; mf < 4; mf++) wacc[et][mf] = MFMA_F16(af[mf], bfp[et][ks], wacc[et][mf]);
      }
      #pragma unroll
      for (int et = 0; et < 2; et++)
        #pragma unroll
        for (int mf = 0; mf < 4; mf++)
          #pragma unroll
          for (int r = 0; r < 4; r++)
            shW[(mf * 16 + quad * 4 + r) * 264 + w * 32 + et * 16 + l16] = (half_t)wacc[et][mf][r];
    }
    __syncthreads();
    // --- prefetch next head's Mt into bfp (all waves; in flight during S-phase) ---
    if (hh < 3) {
      const half_t* Mn = Mt + (size_t)(hbase + hh + 1) * 65536;
      #pragma unroll
      for (int et = 0; et < 2; et++)
        #pragma unroll
        for (int ks = 0; ks < 8; ks++)
          bfp[et][ks] = *(const frag8*)&Mn[(size_t)(w * 32 + et * 16 + l16) * 256 + ks * 32 + quad * 8];
      __builtin_amdgcn_sched_barrier(0);   // don't sink the prefetch into/below the S-phase
    }
    // --- S = W @ A_g^T (contraction over e=256) + softmax; waves 0-3, m = w*16 + l16 ---
    if (w < 4) {
      f32x4 sacc[4];
      #pragma unroll
      for (int zt = 0; zt < 4; zt++) sacc[zt] = (f32x4){0.f, 0.f, 0.f, 0.f};
      frag8 wf_all[8];
      #pragma unroll
      for (int ks = 0; ks < 8; ks++)
        wf_all[ks] = *(const frag8*)&shW[(w * 16 + l16) * 264 + ks * 32 + quad * 8];
      #pragma unroll
      for (int ks = 0; ks < 8; ks++) {
        int k0 = ks * 32 + quad * 8;
        #pragma unroll
        for (int zt = 0; zt < 4; zt++) {
          frag8 kf = *(const frag8*)&shA[(zt * 16 + l16) * 264 + k0];
          sacc[zt] = MFMA_F16(wf_all[ks], kf, sacc[zt]);
        }
      }
      #pragma unroll
      for (int r = 0; r < 4; r++) {
        float mx = fmaxf(fmaxf(sacc[0][r], sacc[1][r]), fmaxf(sacc[2][r], sacc[3][r]));
        #pragma unroll
        for (int off = 1; off < 16; off <<= 1) mx = fmaxf(mx, __shfl_xor(mx, off));
        float e0 = __expf(sacc[0][r] - mx), e1 = __expf(sacc[1][r] - mx);
        float e2 = __expf(sacc[2][r] - mx), e3 = __expf(sacc[3][r] - mx);
        float sum = e0 + e1 + e2 + e3;
        #pragma unroll
        for (int off = 1; off < 16; off <<= 1) sum += __shfl_xor(sum, off);
        float inv = 1.f / sum;
        int m = w * 16 + quad * 4 + r;
        shP[m * 72 + l16 +  0] = (half_t)(e0 * inv);
        shP[m * 72 + l16 + 16] = (half_t)(e1 * inv);
        shP[m * 72 + l16 + 32] = (half_t)(e2 * inv);
        shP[m * 72 + l16 + 48] = (half_t)(e3 * inv);
      }
    }
    __syncthreads();
    // --- PV: O[m][vout] = P @ VT^T (VT in registers); zacc += O * os[h] ---
    // No barrier after PV: next W-phase writes only shW (disjoint from shP), and the
    // post-W barrier orders all PV shP reads before the next S-phase shP writes.
    #pragma unroll
    for (int mf = 0; mf < 4; mf++) {
      frag8 pf0 = *(const frag8*)&shP[(mf * 16 + l16) * 72 +  0 + quad * 8];
      frag8 pf1 = *(const frag8*)&shP[(mf * 16 + l16) * 72 + 32 + quad * 8];
      #pragma unroll
      for (int dt = 0; dt < 2; dt++) {
        f32x4 oacc = (f32x4){0.f, 0.f, 0.f, 0.f};
        oacc = MFMA_F16(pf0, vtreg[dt][0], oacc);
        oacc = MFMA_F16(pf1, vtreg[dt][1], oacc);
        #pragma unroll
        for (int r = 0; r < 4; r++) zacc[mf][dt][r] += oacc[r] * osv[hh][dt];
      }
    }
  }

  // --- Z writeback: stage f16 into shA (dead after last S-phase), coalesced 16B stores ---
  #pragma unroll
  for (int mf = 0; mf < 4; mf++)
    #pragma unroll
    for (int dt = 0; dt < 2; dt++)
      #pragma unroll
      for (int r = 0; r < 4; r++)
        shA[(mf * 16 + quad * 4 + r) * 264 + w * 32 + dt * 16 + l16] = (half_t)zacc[mf][dt][r];
  __syncthreads();
  #pragma unroll
  for (int i = 0; i < 4; i++) {
    int slot = i * 512 + tid;
    int grow = slot >> 5, c8 = (slot & 31) * 8;
    size_t zrow = mode ? ((size_t)(b * 64 + slice) * 64 + grow) : ((size_t)(b * 64 + grow) * 64 + slice);
    *(frag8*)&Z[zrow * 256 + c8] = *(const frag8*)&shA[grow * 264 + c8];
  }
}

// ---------------- residual + LN2; x2 -> d_out fp32, h -> f16 (Z = Z0 + Z1, BLOCKED layout) ----------------
__global__ __launch_bounds__(256) void ln2_kernel(
    const float* __restrict__ x, const half_t* __restrict__ Z0, const half_t* __restrict__ Z1,
    const float* __restrict__ w, const float* __restrict__ bia,
    float* __restrict__ x2out, half_t* __restrict__ hH) {
  int row  = blockIdx.x * 4 + (threadIdx.x >> 6);
  int lane = threadIdx.x & 63;
  size_t base = (size_t)row * 256 + lane * 4;
  int bb = row >> 12, p = row & 4095, hh = p >> 6, ww = p & 63;
  int m = (hh & 7) * 8 + (ww & 7), n = (hh >> 3) * 8 + (ww >> 3);
  size_t zbase = ((size_t)((bb * 64 + m) * 64 + n)) * 256 + lane * 4;
  float4 xv = *(const float4*)&x[base];
  half4_t zv0 = *(const half4_t*)&Z0[zbase];
  half4_t zv1 = *(const half4_t*)&Z1[zbase];
  float4 v;
  v.x = xv.x + (float)zv0[0] + (float)zv1[0];
  v.y = xv.y + (float)zv0[1] + (float)zv1[1];
  v.z = xv.z + (float)zv0[2] + (float)zv1[2];
  v.w = xv.w + (float)zv0[3] + (float)zv1[3];
  float s  = v.x + v.y + v.z + v.w;
  float sq = v.x * v.x + v.y * v.y + v.z * v.z + v.w * v.w;
  #pragma unroll
  for (int off = 1; off < 64; off <<= 1) { s += __shfl_xor(s, off); sq += __shfl_xor(sq, off); }
  float mean = s * (1.f / 256), var = sq * (1.f / 256) - mean * mean;
  float r = rsqrtf(var + EPSc);
  float4 wv = *(const float4*)&w[lane * 4];
  float4 bv = *(const float4*)&bia[lane * 4];
  *(float4*)&x2out[base] = v;
  half4_t y;
  y[0] = (half_t)((v.x - mean) * r * wv.x + bv.x);
  y[1] = (half_t)((v.y - mean) * r * wv.y + bv.y);
  y[2] = (half_t)((v.z - mean) * r * wv.z + bv.z);
  y[3] = (half_t)((v.w - mean) * r * wv.w + bv.w);
  *(half4_t*)&hH[base] = y;
}

extern "C" void kernel_launch(void* const* d_in, const int* in_sizes, int n_in,
                              void* d_out, int out_size, void* d_ws, size_t ws_size,
                              hipStream_t stream) {
  (void)in_sizes; (void)n_in; (void)out_size; (void)ws_size;
  const float* x    = (const float*)d_in[0];
  const float* ln1w = (const float*)d_in[1];
  const float* ln1b = (const float*)d_in[2];
  const float* q    = (const float*)d_in[3];
  const float* k    = (const float*)d_in[4];
  const float* v    = (const float*)d_in[5];
  const float* o    = (const float*)d_in[6];
  const float* ln2w = (const float*)d_in[7];
  const float* ln2b = (const float*)d_in[8];
  const float* w1   = (const float*)d_in[9];
  const float* b1   = (const float*)d_in[10];
  const float* w2   = (const float*)d_in[11];
  const float* b2   = (const float*)d_in[12];
  float* out = (float*)d_out;

  const size_t ROWS = (size_t)Bc * Tc;        // 32768
  const size_t ELTS = ROWS * Dc;              // 8,388,608
  const size_t MB16 = ELTS * sizeof(half_t);  // 16 MiB
  char* ws = (char*)d_ws;
  float*  osumB = (float*)ws;
  half_t* Mt    = (half_t*)(ws + (64 << 10));
  half_t* vt    = (half_t*)(ws + (64 << 10) + (1 << 20));
  half_t* w1t   = (half_t*)(ws + (64 << 10) + (1 << 20) + (128 << 10));
  half_t* w2t   = (half_t*)(ws + (64 << 10) + (1 << 20) + (256 << 10));
  half_t* aH    = (half_t*)(ws + (2 << 20));
  half_t* Zb0   = (half_t*)(ws + (2 << 20) + MB16);
  half_t* Zb1   = (half_t*)(ws + (2 << 20) + 2 * MB16);
  half_t* hH    = aH;   // reuse (a dead after attention)
  half_t* tH    = Zb1;  // reuse (Z1 dead after ln2)

  osum_kernel <<<8,   256, 0, stream>>>(o, osumB);
  prepM_kernel<<<512, 256, 0, stream>>>(q, k, Mt);
  prepT_kernel<<<768, 256, 0, stream>>>(v, w1, w2, vt, w1t, w2t);
  ln1_kernel  <<<ROWS / 4, 256, 0, stream>>>(x, ln1w, ln1b, aH);
  // fused attention: ONE dispatch, 1024 blocks (512 mode-0 -> Z0, 512 mode-1 -> Z1)
  attn_kernel <<<1024, 512, 0, stream>>>(aH, Mt, vt, osumB, Zb0, Zb1);
  // residual + LN2 (sums Z0+Z1 in fp32)
  ln2_kernel  <<<ROWS / 4, 256, 0, stream>>>(x, Zb0, Zb1, ln2w, ln2b, out, hH);
  // MLP on the tiled GEMM: fc1 relu -> tH; fc2 +bias +resid -> out
  wgemm_kernel<<<512, 256, 0, stream>>>(hH, w1t, b1, nullptr, tH, 1, 256, 256);
  wgemm_kernel<<<512, 256, 0, stream>>>(tH, w2t, b2, out, nullptr, 2, 256, 256);
}